// Round 1
// baseline (1213.715 us; speedup 1.0000x reference)
//
#include <hip/hip_runtime.h>
#include <hip/hip_bf16.h>

// Problem constants (fixed by setup_inputs)
#define BQ      2
#define QLEN    16384            // 128*128
#define CDIM    256
#define HEADS   8
#define LEV     3
#define PTS     4
#define DHEAD   32
#define NVTOT   13125            // 100*100 + 50*50 + 25*25
#define FDIM    1024
#define NTOK    (BQ*QLEN)        // 32768
#define MROWS_V (BQ*NVTOT)       // 26250

__device__ __forceinline__ int imin(int a, int b){ return a<b?a:b; }
__device__ __forceinline__ int imax(int a, int b){ return a>b?a:b; }

// ---------------------------------------------------------------- LayerNorm (+optional pos add)
// one wave per token, 4 tokens per 256-thread block
__global__ __launch_bounds__(256)
void ln_k(const float* __restrict__ x, const float* __restrict__ pos,
          const float* __restrict__ g, const float* __restrict__ b,
          float* __restrict__ out)
{
    int tok  = blockIdx.x * 4 + (threadIdx.x >> 6);
    int lane = threadIdx.x & 63;
    const float4* xp = (const float4*)(x + (size_t)tok * CDIM);
    float4 v = xp[lane];
    float s = v.x + v.y + v.z + v.w;
    #pragma unroll
    for (int o = 32; o > 0; o >>= 1) s += __shfl_down(s, o);
    s = __shfl(s, 0);
    float mean = s * (1.0f / 256.0f);
    float4 c; c.x = v.x - mean; c.y = v.y - mean; c.z = v.z - mean; c.w = v.w - mean;
    float q2 = c.x*c.x + c.y*c.y + c.z*c.z + c.w*c.w;
    #pragma unroll
    for (int o = 32; o > 0; o >>= 1) q2 += __shfl_down(q2, o);
    q2 = __shfl(q2, 0);
    float rstd = rsqrtf(q2 * (1.0f / 256.0f) + 1e-5f);
    float4 gg = ((const float4*)g)[lane];
    float4 bb = ((const float4*)b)[lane];
    float4 o4;
    o4.x = c.x * rstd * gg.x + bb.x;
    o4.y = c.y * rstd * gg.y + bb.y;
    o4.z = c.z * rstd * gg.z + bb.z;
    o4.w = c.w * rstd * gg.w + bb.w;
    if (pos) {
        float4 p = ((const float4*)(pos + (size_t)tok * CDIM))[lane];
        o4.x += p.x; o4.y += p.y; o4.z += p.z; o4.w += p.w;
    }
    ((float4*)(out + (size_t)tok * CDIM))[lane] = o4;
}

// ---------------------------------------------------------------- generic fp32 GEMM
// C[M,N] = A[M,K] @ B[K,N] (+bias) with epilogue modes.
// 128x128 block tile, 16 k-tile, 256 threads, 8x8 microtile.
#define BM 128
#define BN 128
#define BKT 16
enum { EP_PLAIN = 0, EP_VSCAT = 1, EP_RES = 2, EP_GELU = 3 };

__global__ __launch_bounds__(256)
void gemm_k(const float* __restrict__ A, const float* __restrict__ Bm,
            const float* __restrict__ bias, const float* __restrict__ res,
            float* __restrict__ Cout, int M, int N, int K, int mode)
{
    __shared__ float As[BKT][BM];
    __shared__ float Bs[BKT][BN];
    int t  = threadIdx.x;
    int tx = t & 15, ty = t >> 4;
    int m0 = blockIdx.y * BM;
    int n0 = blockIdx.x * BN;

    float acc[8][8];
    #pragma unroll
    for (int i = 0; i < 8; i++)
        #pragma unroll
        for (int j = 0; j < 8; j++) acc[i][j] = 0.0f;

    int ar  = t >> 1;            // 0..127
    int akq = (t & 1) * 8;       // 0 or 8
    int bkr = ty;                // 0..15
    int bnq = tx * 8;            // 0..120

    for (int kt = 0; kt < K; kt += BKT) {
        // A tile: 128 rows x 16 k
        {
            int row = m0 + ar;
            if (row < M) {
                const float* ap = A + (size_t)row * K + kt + akq;
                float4 a0 = *(const float4*)ap;
                float4 a1 = *(const float4*)(ap + 4);
                As[akq + 0][ar] = a0.x; As[akq + 1][ar] = a0.y;
                As[akq + 2][ar] = a0.z; As[akq + 3][ar] = a0.w;
                As[akq + 4][ar] = a1.x; As[akq + 5][ar] = a1.y;
                As[akq + 6][ar] = a1.z; As[akq + 7][ar] = a1.w;
            } else {
                #pragma unroll
                for (int i = 0; i < 8; i++) As[akq + i][ar] = 0.0f;
            }
        }
        // B tile: 16 k x 128 cols
        {
            int col = n0 + bnq;
            const float* bp = Bm + (size_t)(kt + bkr) * N + col;
            if (col + 7 < N) {
                *(float4*)&Bs[bkr][bnq]     = *(const float4*)bp;
                *(float4*)&Bs[bkr][bnq + 4] = *(const float4*)(bp + 4);
            } else {
                #pragma unroll
                for (int i = 0; i < 8; i++) {
                    float vv = 0.0f;
                    if (col + i < N) vv = bp[i];
                    Bs[bkr][bnq + i] = vv;
                }
            }
        }
        __syncthreads();
        #pragma unroll
        for (int k = 0; k < BKT; k++) {
            float4 a0 = *(const float4*)&As[k][ty * 8];
            float4 a1 = *(const float4*)&As[k][ty * 8 + 4];
            float4 b0 = *(const float4*)&Bs[k][tx * 8];
            float4 b1 = *(const float4*)&Bs[k][tx * 8 + 4];
            float av[8] = {a0.x, a0.y, a0.z, a0.w, a1.x, a1.y, a1.z, a1.w};
            float bv[8] = {b0.x, b0.y, b0.z, b0.w, b1.x, b1.y, b1.z, b1.w};
            #pragma unroll
            for (int i = 0; i < 8; i++)
                #pragma unroll
                for (int j = 0; j < 8; j++)
                    acc[i][j] += av[i] * bv[j];
        }
        __syncthreads();
    }

    #pragma unroll
    for (int i = 0; i < 8; i++) {
        int row = m0 + ty * 8 + i;
        if (row >= M) continue;
        #pragma unroll
        for (int j = 0; j < 8; j++) {
            int col = n0 + tx * 8 + j;
            if (col >= N) continue;
            float vv = acc[i][j];
            if (bias) vv += bias[col];
            if (mode == EP_RES) {
                vv += res[(size_t)row * N + col];
            } else if (mode == EP_GELU) {
                vv = 0.5f * vv * (1.0f + erff(vv * 0.70710678118654752f));
            }
            if (mode == EP_VSCAT) {
                int bb  = row / NVTOT;
                int pix = row - bb * NVTOT;
                int hh  = col >> 5, dc = col & 31;
                Cout[(((size_t)(bb * HEADS + hh)) * NVTOT + pix) * DHEAD + dc] = vv;
            } else {
                Cout[(size_t)row * N + col] = vv;
            }
        }
    }
}

// ---------------------------------------------------------------- softmax over 12 (per token*head)
__global__ __launch_bounds__(256)
void softmax_k(float* __restrict__ a, int n)
{
    int i = blockIdx.x * 256 + threadIdx.x;
    if (i >= n) return;
    float* p = a + (size_t)i * 12;
    float v[12];
    float m = -1e30f;
    #pragma unroll
    for (int j = 0; j < 12; j++) { v[j] = p[j]; m = fmaxf(m, v[j]); }
    float s = 0.0f;
    #pragma unroll
    for (int j = 0; j < 12; j++) { v[j] = expf(v[j] - m); s += v[j]; }
    float r = 1.0f / s;
    #pragma unroll
    for (int j = 0; j < 12; j++) p[j] = v[j] * r;
}

// ---------------------------------------------------------------- deformable sampling
// one block per token; thread = (head, channel)
__global__ __launch_bounds__(256)
void sample_k(const float* __restrict__ v, const float* __restrict__ off,
              const float* __restrict__ attn, const float* __restrict__ ref,
              float* __restrict__ out)
{
    const int HW[3]     = {100, 50, 25};
    const int STARTS[3] = {0, 10000, 12500};
    int t = blockIdx.x;                // token 0..32767
    int h = threadIdx.x >> 5;
    int c = threadIdx.x & 31;
    int b = t >> 14;
    float rx = ref[(size_t)t * 2 + 0];
    float ry = ref[(size_t)t * 2 + 1];
    const float* vbh  = v + ((size_t)(b * HEADS + h)) * NVTOT * DHEAD;
    const float* offp = off + (size_t)t * (HEADS * LEV * PTS * 2) + h * (LEV * PTS * 2);
    const float* awp  = attn + (size_t)t * (HEADS * LEV * PTS) + h * (LEV * PTS);
    float acc = 0.0f;
    #pragma unroll
    for (int l = 0; l < 3; l++) {
        int Wl = HW[l], Hl = HW[l];
        int st = STARTS[l];
        float fW = (float)Wl, fH = (float)Hl;
        #pragma unroll
        for (int p = 0; p < 4; p++) {
            float ox = offp[(l * 4 + p) * 2 + 0];
            float oy = offp[(l * 4 + p) * 2 + 1];
            float aw = awp[l * 4 + p];
            float lx = rx + ox / fW;
            float ly = ry + oy / fH;
            float x = lx * fW - 0.5f;
            float y = ly * fH - 0.5f;
            float x0f = floorf(x), y0f = floorf(y);
            float fx = x - x0f, fy = y - y0f;
            int x0 = (int)x0f, y0 = (int)y0f;
            int x1 = x0 + 1,  y1 = y0 + 1;
            int cx0 = imin(imax(x0, 0), Wl - 1), cx1 = imin(imax(x1, 0), Wl - 1);
            int cy0 = imin(imax(y0, 0), Hl - 1), cy1 = imin(imax(y1, 0), Hl - 1);
            bool vx0 = (x0 >= 0) & (x0 < Wl), vx1 = (x1 >= 0) & (x1 < Wl);
            bool vy0 = (y0 >= 0) & (y0 < Hl), vy1 = (y1 >= 0) & (y1 < Hl);
            float w00 = (1.0f - fx) * (1.0f - fy);
            float w01 = fx * (1.0f - fy);
            float w10 = (1.0f - fx) * fy;
            float w11 = fx * fy;
            float g00 = (vx0 && vy0) ? vbh[(size_t)(st + cy0 * Wl + cx0) * DHEAD + c] : 0.0f;
            float g01 = (vx1 && vy0) ? vbh[(size_t)(st + cy0 * Wl + cx1) * DHEAD + c] : 0.0f;
            float g10 = (vx0 && vy1) ? vbh[(size_t)(st + cy1 * Wl + cx0) * DHEAD + c] : 0.0f;
            float g11 = (vx1 && vy1) ? vbh[(size_t)(st + cy1 * Wl + cx1) * DHEAD + c] : 0.0f;
            acc += aw * (w00 * g00 + w01 * g01 + w10 * g10 + w11 * g11);
        }
    }
    out[(size_t)t * CDIM + h * DHEAD + c] = acc;
}

// ---------------------------------------------------------------- launch
extern "C" void kernel_launch(void* const* d_in, const int* in_sizes, int n_in,
                              void* d_out, int out_size, void* d_ws, size_t ws_size,
                              hipStream_t stream)
{
    const float* query = (const float*)d_in[0];
    const float* value = (const float*)d_in[1];
    const float* qpos  = (const float*)d_in[2];
    const float* ref   = (const float*)d_in[3];
    const float* ln1g  = (const float*)d_in[6];
    const float* ln1b  = (const float*)d_in[7];
    const float* ln2g  = (const float*)d_in[8];
    const float* ln2b  = (const float*)d_in[9];
    const float* Wv    = (const float*)d_in[10];
    const float* bv    = (const float*)d_in[11];
    const float* Woff  = (const float*)d_in[12];
    const float* boff  = (const float*)d_in[13];
    const float* Wat   = (const float*)d_in[14];
    const float* bat   = (const float*)d_in[15];
    const float* Wout  = (const float*)d_in[16];
    const float* bout  = (const float*)d_in[17];
    const float* W1    = (const float*)d_in[18];
    const float* b1    = (const float*)d_in[19];
    const float* W2    = (const float*)d_in[20];
    const float* b2    = (const float*)d_in[21];
    float* out = (float*)d_out;
    char*  ws  = (char*)d_ws;

    // workspace layout (bytes); union region reused for gelu acts
    const size_t SZ_Q    = (size_t)NTOK * CDIM * 4;            // 33,554,432  q / h
    const size_t SZ_V    = (size_t)BQ * HEADS * NVTOT * DHEAD * 4; // 26,880,000
    const size_t SZ_OFF  = (size_t)NTOK * 192 * 4;             // 25,165,824
    const size_t SZ_ATTN = (size_t)NTOK * 96 * 4;              // 12,582,912
    const size_t OFF_Q    = 0;
    const size_t OFF_U    = SZ_Q;
    const size_t OFF_V    = OFF_U;
    const size_t OFF_OFFS = OFF_V + SZ_V;
    const size_t OFF_ATTN = OFF_OFFS + SZ_OFF;
    const size_t OFF_AOUT = OFF_ATTN + SZ_ATTN;
    const size_t OFF_G    = OFF_U;                              // aliases v/off/attn/aout

    float* qbuf  = (float*)(ws + OFF_Q);
    float* vbuf  = (float*)(ws + OFF_V);
    float* obuf  = (float*)(ws + OFF_OFFS);
    float* abuf  = (float*)(ws + OFF_ATTN);
    float* aout  = (float*)(ws + OFF_AOUT);
    float* gbuf  = (float*)(ws + OFF_G);
    float* hbuf  = qbuf;   // reuse after q is consumed

    // 1. q = LN1(query) + query_pos
    ln_k<<<NTOK / 4, 256, 0, stream>>>(query, qpos, ln1g, ln1b, qbuf);
    // 2. v = value @ W_value + b_value, scattered to [b][h][pix][d]
    gemm_k<<<dim3(2, (MROWS_V + BM - 1) / BM), 256, 0, stream>>>(
        value, Wv, bv, nullptr, vbuf, MROWS_V, 256, 256, EP_VSCAT);
    // 3. offsets = q @ W_off + b_off
    gemm_k<<<dim3(2, NTOK / BM), 256, 0, stream>>>(
        qbuf, Woff, boff, nullptr, obuf, NTOK, 192, 256, EP_PLAIN);
    // 4. attn logits = q @ W_attn + b_attn
    gemm_k<<<dim3(1, NTOK / BM), 256, 0, stream>>>(
        qbuf, Wat, bat, nullptr, abuf, NTOK, 96, 256, EP_PLAIN);
    // 5. softmax over 12 per (token, head)
    softmax_k<<<(NTOK * HEADS) / 256, 256, 0, stream>>>(abuf, NTOK * HEADS);
    // 6. deformable sampling -> aout [t][C]
    sample_k<<<NTOK, 256, 0, stream>>>(vbuf, obuf, abuf, ref, aout);
    // 7. x = query + aout @ W_out + b_out   -> d_out
    gemm_k<<<dim3(2, NTOK / BM), 256, 0, stream>>>(
        aout, Wout, bout, query, out, NTOK, 256, 256, EP_RES);
    // 8. h = LN2(x)
    ln_k<<<NTOK / 4, 256, 0, stream>>>(out, nullptr, ln2g, ln2b, hbuf);
    // 9. g = gelu(h @ W_ffn1 + b_ffn1)
    gemm_k<<<dim3(FDIM / BN, NTOK / BM), 256, 0, stream>>>(
        hbuf, W1, b1, nullptr, gbuf, NTOK, FDIM, 256, EP_GELU);
    // 10. out = x + g @ W_ffn2 + b_ffn2  (in-place residual on d_out)
    gemm_k<<<dim3(2, NTOK / BM), 256, 0, stream>>>(
        gbuf, W2, b2, out, out, NTOK, 256, FDIM, EP_RES);
}

// Round 2
// 705.997 us; speedup vs baseline: 1.7191x; 1.7191x over previous
//
#include <hip/hip_runtime.h>
#include <hip/hip_bf16.h>

// Problem constants (fixed by setup_inputs)
#define BQ      2
#define QLEN    16384            // 128*128
#define CDIM    256
#define HEADS   8
#define LEV     3
#define PTS     4
#define DHEAD   32
#define NVTOT   13125            // 100*100 + 50*50 + 25*25
#define FDIM    1024
#define NTOK    (BQ*QLEN)        // 32768
#define MROWS_V (BQ*NVTOT)       // 26250

typedef __attribute__((ext_vector_type(8))) short short8;     // 8 bf16 = 4 VGPRs
typedef __attribute__((ext_vector_type(4))) float floatx4;    // MFMA acc

typedef const __attribute__((address_space(1))) unsigned int gu32;
typedef __attribute__((address_space(3))) unsigned int lu32;

struct bf16x4 { __hip_bfloat16 v[4]; };

__device__ __forceinline__ int imin(int a, int b){ return a<b?a:b; }
__device__ __forceinline__ int imax(int a, int b){ return a>b?a:b; }

// ---------------------------------------------------------------- LayerNorm (+optional pos add), bf16 out
// one wave per token, 4 tokens per 256-thread block
__global__ __launch_bounds__(256)
void ln_bf16_k(const float* __restrict__ x, const float* __restrict__ pos,
               const float* __restrict__ g, const float* __restrict__ b,
               __hip_bfloat16* __restrict__ out)
{
    int tok  = blockIdx.x * 4 + (threadIdx.x >> 6);
    int lane = threadIdx.x & 63;
    float4 v = ((const float4*)(x + (size_t)tok * CDIM))[lane];
    float s = v.x + v.y + v.z + v.w;
    #pragma unroll
    for (int o = 32; o > 0; o >>= 1) s += __shfl_down(s, o);
    s = __shfl(s, 0);
    float mean = s * (1.0f / 256.0f);
    float4 c; c.x = v.x - mean; c.y = v.y - mean; c.z = v.z - mean; c.w = v.w - mean;
    float q2 = c.x*c.x + c.y*c.y + c.z*c.z + c.w*c.w;
    #pragma unroll
    for (int o = 32; o > 0; o >>= 1) q2 += __shfl_down(q2, o);
    q2 = __shfl(q2, 0);
    float rstd = rsqrtf(q2 * (1.0f / 256.0f) + 1e-5f);
    float4 gg = ((const float4*)g)[lane];
    float4 bb = ((const float4*)b)[lane];
    float4 o4;
    o4.x = c.x * rstd * gg.x + bb.x;
    o4.y = c.y * rstd * gg.y + bb.y;
    o4.z = c.z * rstd * gg.z + bb.z;
    o4.w = c.w * rstd * gg.w + bb.w;
    if (pos) {
        float4 p = ((const float4*)(pos + (size_t)tok * CDIM))[lane];
        o4.x += p.x; o4.y += p.y; o4.z += p.z; o4.w += p.w;
    }
    bf16x4 r;
    r.v[0] = __float2bfloat16(o4.x); r.v[1] = __float2bfloat16(o4.y);
    r.v[2] = __float2bfloat16(o4.z); r.v[3] = __float2bfloat16(o4.w);
    ((bf16x4*)(out + (size_t)tok * CDIM))[lane] = r;
}

// ---------------------------------------------------------------- fp32 -> bf16 convert
__global__ __launch_bounds__(256)
void cvt_k(const float* __restrict__ in, __hip_bfloat16* __restrict__ out, int n4)
{
    int i = blockIdx.x * 256 + threadIdx.x;
    if (i >= n4) return;
    float4 v = ((const float4*)in)[i];
    bf16x4 r;
    r.v[0] = __float2bfloat16(v.x); r.v[1] = __float2bfloat16(v.y);
    r.v[2] = __float2bfloat16(v.z); r.v[3] = __float2bfloat16(v.w);
    ((bf16x4*)out)[i] = r;
}

// ---------------------------------------------------------------- weight transpose+convert: W[K][N] fp32 -> Wt[Npad][K] bf16 (pad rows zero)
__global__ __launch_bounds__(256)
void wt_k(const float* __restrict__ W, __hip_bfloat16* __restrict__ Wt,
          int K, int N, int Npad)
{
    int idx = blockIdx.x * 256 + threadIdx.x;
    if (idx >= Npad * K) return;
    int n = idx / K, k = idx - n * K;
    float v = (n < N) ? W[(size_t)k * N + n] : 0.0f;
    Wt[idx] = __float2bfloat16(v);
}

// ---------------------------------------------------------------- bf16 MFMA GEMM (m97 structure)
// C[M,N] = A[M,K](bf16) @ Bt[N][K](bf16)^T + bias, epilogue modes.
// 128x128 tile, BK=32, 256 threads = 2x2 waves, each wave 4x4 of 16x16x32 MFMA.
enum { EP_PLAIN = 0, EP_VSCAT = 1, EP_RES = 2, EP_GELU_BF16 = 3 };

__global__ __launch_bounds__(256)
void mm_k(const __hip_bfloat16* __restrict__ A, const __hip_bfloat16* __restrict__ Bt,
          const float* __restrict__ bias, const float* __restrict__ res,
          void* __restrict__ Cout, int M, int N, int K, int mode)
{
    __shared__ __hip_bfloat16 As[128 * 32];
    __shared__ __hip_bfloat16 Bs[128 * 32];
    int t = threadIdx.x;
    int lane = t & 63;
    int wave = t >> 6;
    int wm = wave >> 1, wn = wave & 1;
    int lm = lane & 15, lk = lane >> 4;
    int m0 = blockIdx.y * 128;
    int n0 = blockIdx.x * 128;

    floatx4 acc[4][4];
    #pragma unroll
    for (int i = 0; i < 4; i++)
        #pragma unroll
        for (int j = 0; j < 4; j++) acc[i][j] = (floatx4)0.0f;

    for (int kt = 0; kt < K; kt += 32) {
        #pragma unroll
        for (int i = 0; i < 2; i++) {
            int cc  = i * 256 + t;          // chunk id, 16B each
            int row = cc >> 2;
            int ko  = (cc & 3) * 8;
            int ra  = m0 + row; if (ra >= M) ra = M - 1;   // clamp: garbage rows only hit discarded C rows
            const __hip_bfloat16* ga = A  + (size_t)ra * K + kt + ko;
            const __hip_bfloat16* gb = Bt + (size_t)(n0 + row) * K + kt + ko;
            __builtin_amdgcn_global_load_lds((gu32*)ga, (lu32*)(As + cc * 8), 16, 0, 0);
            __builtin_amdgcn_global_load_lds((gu32*)gb, (lu32*)(Bs + cc * 8), 16, 0, 0);
        }
        __syncthreads();
        short8 af[4], bfr[4];
        #pragma unroll
        for (int i = 0; i < 4; i++) {
            af[i]  = *(const short8*)(As + (wm * 64 + i * 16 + lm) * 32 + lk * 8);
            bfr[i] = *(const short8*)(Bs + (wn * 64 + i * 16 + lm) * 32 + lk * 8);
        }
        #pragma unroll
        for (int i = 0; i < 4; i++)
            #pragma unroll
            for (int j = 0; j < 4; j++)
                acc[i][j] = __builtin_amdgcn_mfma_f32_16x16x32_bf16(af[i], bfr[j], acc[i][j], 0, 0, 0);
        __syncthreads();
    }

    // epilogue: C/D map col=lane&15, row=(lane>>4)*4+reg  [verified m89]
    #pragma unroll
    for (int i = 0; i < 4; i++) {
        #pragma unroll
        for (int j = 0; j < 4; j++) {
            int col = n0 + wn * 64 + j * 16 + lm;
            if (col >= N) continue;
            float bv = bias ? bias[col] : 0.0f;
            #pragma unroll
            for (int r = 0; r < 4; r++) {
                int row = m0 + wm * 64 + i * 16 + lk * 4 + r;
                if (row >= M) continue;
                float v = acc[i][j][r] + bv;
                if (mode == EP_PLAIN) {
                    ((float*)Cout)[(size_t)row * N + col] = v;
                } else if (mode == EP_VSCAT) {
                    int bb  = row / NVTOT;
                    int pix = row - bb * NVTOT;
                    int hh  = col >> 5, dc = col & 31;
                    ((float*)Cout)[(((size_t)(bb * HEADS + hh)) * NVTOT + pix) * DHEAD + dc] = v;
                } else if (mode == EP_RES) {
                    ((float*)Cout)[(size_t)row * N + col] = v + res[(size_t)row * N + col];
                } else { // EP_GELU_BF16
                    float gl = 0.5f * v * (1.0f + erff(v * 0.70710678118654752f));
                    ((__hip_bfloat16*)Cout)[(size_t)row * N + col] = __float2bfloat16(gl);
                }
            }
        }
    }
}

// ---------------------------------------------------------------- softmax over 12 (per token*head)
__global__ __launch_bounds__(256)
void softmax_k(float* __restrict__ a, int n)
{
    int i = blockIdx.x * 256 + threadIdx.x;
    if (i >= n) return;
    float* p = a + (size_t)i * 12;
    float v[12];
    float m = -1e30f;
    #pragma unroll
    for (int j = 0; j < 12; j++) { v[j] = p[j]; m = fmaxf(m, v[j]); }
    float s = 0.0f;
    #pragma unroll
    for (int j = 0; j < 12; j++) { v[j] = expf(v[j] - m); s += v[j]; }
    float r = 1.0f / s;
    #pragma unroll
    for (int j = 0; j < 12; j++) p[j] = v[j] * r;
}

// ---------------------------------------------------------------- deformable sampling (bf16 out)
__global__ __launch_bounds__(256)
void sample_k(const float* __restrict__ v, const float* __restrict__ off,
              const float* __restrict__ attn, const float* __restrict__ ref,
              __hip_bfloat16* __restrict__ out)
{
    const int HW[3]     = {100, 50, 25};
    const int STARTS[3] = {0, 10000, 12500};
    int t = blockIdx.x;
    int h = threadIdx.x >> 5;
    int c = threadIdx.x & 31;
    int b = t >> 14;
    float rx = ref[(size_t)t * 2 + 0];
    float ry = ref[(size_t)t * 2 + 1];
    const float* vbh  = v + ((size_t)(b * HEADS + h)) * NVTOT * DHEAD;
    const float* offp = off + (size_t)t * (HEADS * LEV * PTS * 2) + h * (LEV * PTS * 2);
    const float* awp  = attn + (size_t)t * (HEADS * LEV * PTS) + h * (LEV * PTS);
    float acc = 0.0f;
    #pragma unroll
    for (int l = 0; l < 3; l++) {
        int Wl = HW[l], Hl = HW[l];
        int st = STARTS[l];
        float fW = (float)Wl, fH = (float)Hl;
        #pragma unroll
        for (int p = 0; p < 4; p++) {
            float ox = offp[(l * 4 + p) * 2 + 0];
            float oy = offp[(l * 4 + p) * 2 + 1];
            float aw = awp[l * 4 + p];
            float x = (rx + ox / fW) * fW - 0.5f;
            float y = (ry + oy / fH) * fH - 0.5f;
            float x0f = floorf(x), y0f = floorf(y);
            float fx = x - x0f, fy = y - y0f;
            int x0 = (int)x0f, y0 = (int)y0f;
            int x1 = x0 + 1,  y1 = y0 + 1;
            int cx0 = imin(imax(x0, 0), Wl - 1), cx1 = imin(imax(x1, 0), Wl - 1);
            int cy0 = imin(imax(y0, 0), Hl - 1), cy1 = imin(imax(y1, 0), Hl - 1);
            bool vx0 = (x0 >= 0) & (x0 < Wl), vx1 = (x1 >= 0) & (x1 < Wl);
            bool vy0 = (y0 >= 0) & (y0 < Hl), vy1 = (y1 >= 0) & (y1 < Hl);
            float w00 = (1.0f - fx) * (1.0f - fy);
            float w01 = fx * (1.0f - fy);
            float w10 = (1.0f - fx) * fy;
            float w11 = fx * fy;
            float g00 = (vx0 && vy0) ? vbh[(size_t)(st + cy0 * Wl + cx0) * DHEAD + c] : 0.0f;
            float g01 = (vx1 && vy0) ? vbh[(size_t)(st + cy0 * Wl + cx1) * DHEAD + c] : 0.0f;
            float g10 = (vx0 && vy1) ? vbh[(size_t)(st + cy1 * Wl + cx0) * DHEAD + c] : 0.0f;
            float g11 = (vx1 && vy1) ? vbh[(size_t)(st + cy1 * Wl + cx1) * DHEAD + c] : 0.0f;
            acc += aw * (w00 * g00 + w01 * g01 + w10 * g10 + w11 * g11);
        }
    }
    out[(size_t)t * CDIM + h * DHEAD + c] = __float2bfloat16(acc);
}

// ---------------------------------------------------------------- launch
extern "C" void kernel_launch(void* const* d_in, const int* in_sizes, int n_in,
                              void* d_out, int out_size, void* d_ws, size_t ws_size,
                              hipStream_t stream)
{
    const float* query = (const float*)d_in[0];
    const float* value = (const float*)d_in[1];
    const float* qpos  = (const float*)d_in[2];
    const float* ref   = (const float*)d_in[3];
    const float* ln1g  = (const float*)d_in[6];
    const float* ln1b  = (const float*)d_in[7];
    const float* ln2g  = (const float*)d_in[8];
    const float* ln2b  = (const float*)d_in[9];
    const float* Wv    = (const float*)d_in[10];
    const float* bv    = (const float*)d_in[11];
    const float* Woff  = (const float*)d_in[12];
    const float* boff  = (const float*)d_in[13];
    const float* Wat   = (const float*)d_in[14];
    const float* bat   = (const float*)d_in[15];
    const float* Wout  = (const float*)d_in[16];
    const float* bout  = (const float*)d_in[17];
    const float* W1    = (const float*)d_in[18];
    const float* b1    = (const float*)d_in[19];
    const float* W2    = (const float*)d_in[20];
    const float* b2    = (const float*)d_in[21];
    float* out = (float*)d_out;
    char*  ws  = (char*)d_ws;

    const size_t MB = 1024 * 1024;
    // transposed bf16 weights (2 MB region)
    __hip_bfloat16* Wvt   = (__hip_bfloat16*)(ws + 0);
    __hip_bfloat16* Wofft = (__hip_bfloat16*)(ws + 131072);
    __hip_bfloat16* Watt  = (__hip_bfloat16*)(ws + 262144);
    __hip_bfloat16* Woutt = (__hip_bfloat16*)(ws + 327680);
    __hip_bfloat16* W1t   = (__hip_bfloat16*)(ws + 458752);
    __hip_bfloat16* W2t   = (__hip_bfloat16*)(ws + 983040);
    // activations
    __hip_bfloat16* qbf   = (__hip_bfloat16*)(ws + 2  * MB);  // 16.78 MB; reused as h after q dead
    __hip_bfloat16* aoutb = (__hip_bfloat16*)(ws + 19 * MB);  // 16.78 MB
    __hip_bfloat16* vbf   = (__hip_bfloat16*)(ws + 36 * MB);  // 13.44 MB
    float*          vbuf  = (float*)(ws + 50  * MB);          // 26.88 MB scattered v
    float*          obuf  = (float*)(ws + 77  * MB);          // 25.17 MB offsets
    float*          abuf  = (float*)(ws + 103 * MB);          // 12.58 MB attn
    __hip_bfloat16* gbf   = (__hip_bfloat16*)(ws + 50 * MB);  // 67.1 MB, aliases vbuf/obuf/abuf (dead)
    __hip_bfloat16* hbf   = qbf;

    // 0. weights -> bf16 transposed [Npad][K]
    wt_k<<<65536  / 256, 256, 0, stream>>>(Wv,   Wvt,   256, 256,  256);
    wt_k<<<65536  / 256, 256, 0, stream>>>(Woff, Wofft, 256, 192,  256);
    wt_k<<<32768  / 256, 256, 0, stream>>>(Wat,  Watt,  256, 96,   128);
    wt_k<<<65536  / 256, 256, 0, stream>>>(Wout, Woutt, 256, 256,  256);
    wt_k<<<262144 / 256, 256, 0, stream>>>(W1,   W1t,   256, 1024, 1024);
    wt_k<<<262144 / 256, 256, 0, stream>>>(W2,   W2t,   1024, 256, 256);
    // 0b. value -> bf16
    cvt_k<<<(MROWS_V * CDIM / 4 + 255) / 256, 256, 0, stream>>>(value, vbf, MROWS_V * CDIM / 4);
    // 1. q = LN1(query) + query_pos  (bf16)
    ln_bf16_k<<<NTOK / 4, 256, 0, stream>>>(query, qpos, ln1g, ln1b, qbf);
    // 2. v = value @ W_value + b_value, scattered [b][h][pix][d] fp32
    mm_k<<<dim3(2, (MROWS_V + 127) / 128), 256, 0, stream>>>(
        vbf, Wvt, bv, nullptr, vbuf, MROWS_V, 256, 256, EP_VSCAT);
    // 3. offsets = q @ W_off + b_off  (fp32)
    mm_k<<<dim3(2, NTOK / 128), 256, 0, stream>>>(
        qbf, Wofft, boff, nullptr, obuf, NTOK, 192, 256, EP_PLAIN);
    // 4. attn logits = q @ W_attn + b_attn  (fp32)
    mm_k<<<dim3(1, NTOK / 128), 256, 0, stream>>>(
        qbf, Watt, bat, nullptr, abuf, NTOK, 96, 256, EP_PLAIN);
    // 5. softmax over 12
    softmax_k<<<(NTOK * HEADS) / 256, 256, 0, stream>>>(abuf, NTOK * HEADS);
    // 6. sampling -> aout bf16
    sample_k<<<NTOK, 256, 0, stream>>>(vbuf, obuf, abuf, ref, aoutb);
    // 7. x = query + aout @ W_out + b_out -> d_out fp32
    mm_k<<<dim3(2, NTOK / 128), 256, 0, stream>>>(
        aoutb, Woutt, bout, query, out, NTOK, 256, 256, EP_RES);
    // 8. h = LN2(x)  bf16
    ln_bf16_k<<<NTOK / 4, 256, 0, stream>>>(out, nullptr, ln2g, ln2b, hbf);
    // 9. g = gelu(h @ W_ffn1 + b_ffn1)  bf16
    mm_k<<<dim3(8, NTOK / 128), 256, 0, stream>>>(
        hbf, W1t, b1, nullptr, gbf, NTOK, FDIM, 256, EP_GELU_BF16);
    // 10. out = x + g @ W_ffn2 + b_ffn2  (in-place residual)
    mm_k<<<dim3(2, NTOK / 128), 256, 0, stream>>>(
        gbf, W2t, b2, out, out, NTOK, 256, FDIM, EP_RES);
}

// Round 3
// 501.663 us; speedup vs baseline: 2.4194x; 1.4073x over previous
//
#include <hip/hip_runtime.h>
#include <hip/hip_bf16.h>

// Problem constants (fixed by setup_inputs)
#define BQ      2
#define QLEN    16384            // 128*128
#define CDIM    256
#define HEADS   8
#define LEV     3
#define PTS     4
#define DHEAD   32
#define NVTOT   13125            // 100*100 + 50*50 + 25*25
#define FDIM    1024
#define NTOK    (BQ*QLEN)        // 32768
#define MROWS_V (BQ*NVTOT)       // 26250

typedef __attribute__((ext_vector_type(8))) short short8;     // 8 bf16 = 4 VGPRs
typedef __attribute__((ext_vector_type(4))) float floatx4;    // MFMA acc

typedef const __attribute__((address_space(1))) unsigned int gu32;
typedef __attribute__((address_space(3))) unsigned int lu32;

struct bf16x4 { __hip_bfloat16 v[4]; };

__device__ __forceinline__ int imin(int a, int b){ return a<b?a:b; }
__device__ __forceinline__ int imax(int a, int b){ return a>b?a:b; }

// ---------------------------------------------------------------- LayerNorm (+optional pos add), bf16 out
__global__ __launch_bounds__(256)
void ln_bf16_k(const float* __restrict__ x, const float* __restrict__ pos,
               const float* __restrict__ g, const float* __restrict__ b,
               __hip_bfloat16* __restrict__ out)
{
    int tok  = blockIdx.x * 4 + (threadIdx.x >> 6);
    int lane = threadIdx.x & 63;
    float4 v = ((const float4*)(x + (size_t)tok * CDIM))[lane];
    float s = v.x + v.y + v.z + v.w;
    #pragma unroll
    for (int o = 32; o > 0; o >>= 1) s += __shfl_down(s, o);
    s = __shfl(s, 0);
    float mean = s * (1.0f / 256.0f);
    float4 c; c.x = v.x - mean; c.y = v.y - mean; c.z = v.z - mean; c.w = v.w - mean;
    float q2 = c.x*c.x + c.y*c.y + c.z*c.z + c.w*c.w;
    #pragma unroll
    for (int o = 32; o > 0; o >>= 1) q2 += __shfl_down(q2, o);
    q2 = __shfl(q2, 0);
    float rstd = rsqrtf(q2 * (1.0f / 256.0f) + 1e-5f);
    float4 gg = ((const float4*)g)[lane];
    float4 bb = ((const float4*)b)[lane];
    float4 o4;
    o4.x = c.x * rstd * gg.x + bb.x;
    o4.y = c.y * rstd * gg.y + bb.y;
    o4.z = c.z * rstd * gg.z + bb.z;
    o4.w = c.w * rstd * gg.w + bb.w;
    if (pos) {
        float4 p = ((const float4*)(pos + (size_t)tok * CDIM))[lane];
        o4.x += p.x; o4.y += p.y; o4.z += p.z; o4.w += p.w;
    }
    bf16x4 r;
    r.v[0] = __float2bfloat16(o4.x); r.v[1] = __float2bfloat16(o4.y);
    r.v[2] = __float2bfloat16(o4.z); r.v[3] = __float2bfloat16(o4.w);
    ((bf16x4*)(out + (size_t)tok * CDIM))[lane] = r;
}

// ---------------------------------------------------------------- fp32 -> bf16 convert
__global__ __launch_bounds__(256)
void cvt_k(const float* __restrict__ in, __hip_bfloat16* __restrict__ out, int n4)
{
    int i = blockIdx.x * 256 + threadIdx.x;
    if (i >= n4) return;
    float4 v = ((const float4*)in)[i];
    bf16x4 r;
    r.v[0] = __float2bfloat16(v.x); r.v[1] = __float2bfloat16(v.y);
    r.v[2] = __float2bfloat16(v.z); r.v[3] = __float2bfloat16(v.w);
    ((bf16x4*)out)[i] = r;
}

// ---------------------------------------------------------------- fused weight transpose+convert
// W[K][N] fp32 -> Wt[Npad][K] bf16 for all 6 weights in one launch (fixed dims).
__global__ __launch_bounds__(256)
void wt_all_k(const float* __restrict__ Wv,  const float* __restrict__ Woff,
              const float* __restrict__ Wat, const float* __restrict__ Wout,
              const float* __restrict__ W1,  const float* __restrict__ W2,
              __hip_bfloat16* __restrict__ o_v,  __hip_bfloat16* __restrict__ o_off,
              __hip_bfloat16* __restrict__ o_at, __hip_bfloat16* __restrict__ o_out,
              __hip_bfloat16* __restrict__ o_1,  __hip_bfloat16* __restrict__ o_2)
{
    int gid = blockIdx.x * 256 + threadIdx.x;
    const float* W; __hip_bfloat16* O; int idx, K, N;
    if      (gid < 65536)  { W = Wv;   O = o_v;   idx = gid;          K = 256;  N = 256;  }
    else if (gid < 131072) { W = Woff; O = o_off; idx = gid - 65536;  K = 256;  N = 192;  }
    else if (gid < 163840) { W = Wat;  O = o_at;  idx = gid - 131072; K = 256;  N = 96;   }
    else if (gid < 229376) { W = Wout; O = o_out; idx = gid - 163840; K = 256;  N = 256;  }
    else if (gid < 491520) { W = W1;   O = o_1;   idx = gid - 229376; K = 256;  N = 1024; }
    else if (gid < 753664) { W = W2;   O = o_2;   idx = gid - 491520; K = 1024; N = 256;  }
    else return;
    int n = idx / K, k = idx - n * K;
    float v = (n < N) ? W[(size_t)k * N + n] : 0.0f;
    O[idx] = __float2bfloat16(v);
}

// ---------------------------------------------------------------- bf16 MFMA GEMM (m97 structure)
enum { EP_PLAIN = 0, EP_VSCAT_BF16 = 1, EP_RES = 2, EP_GELU_BF16 = 3 };

__global__ __launch_bounds__(256)
void mm_k(const __hip_bfloat16* __restrict__ A, const __hip_bfloat16* __restrict__ Bt,
          const float* __restrict__ bias, const float* __restrict__ res,
          void* __restrict__ Cout, int M, int N, int K, int mode)
{
    __shared__ __hip_bfloat16 As[128 * 32];
    __shared__ __hip_bfloat16 Bs[128 * 32];
    int t = threadIdx.x;
    int lane = t & 63;
    int wave = t >> 6;
    int wm = wave >> 1, wn = wave & 1;
    int lm = lane & 15, lk = lane >> 4;
    int m0 = blockIdx.y * 128;
    int n0 = blockIdx.x * 128;

    floatx4 acc[4][4];
    #pragma unroll
    for (int i = 0; i < 4; i++)
        #pragma unroll
        for (int j = 0; j < 4; j++) acc[i][j] = (floatx4)0.0f;

    for (int kt = 0; kt < K; kt += 32) {
        #pragma unroll
        for (int i = 0; i < 2; i++) {
            int cc  = i * 256 + t;
            int row = cc >> 2;
            int ko  = (cc & 3) * 8;
            int ra  = m0 + row; if (ra >= M) ra = M - 1;
            const __hip_bfloat16* ga = A  + (size_t)ra * K + kt + ko;
            const __hip_bfloat16* gb = Bt + (size_t)(n0 + row) * K + kt + ko;
            __builtin_amdgcn_global_load_lds((gu32*)ga, (lu32*)(As + cc * 8), 16, 0, 0);
            __builtin_amdgcn_global_load_lds((gu32*)gb, (lu32*)(Bs + cc * 8), 16, 0, 0);
        }
        __syncthreads();
        short8 af[4], bfr[4];
        #pragma unroll
        for (int i = 0; i < 4; i++) {
            af[i]  = *(const short8*)(As + (wm * 64 + i * 16 + lm) * 32 + lk * 8);
            bfr[i] = *(const short8*)(Bs + (wn * 64 + i * 16 + lm) * 32 + lk * 8);
        }
        #pragma unroll
        for (int i = 0; i < 4; i++)
            #pragma unroll
            for (int j = 0; j < 4; j++)
                acc[i][j] = __builtin_amdgcn_mfma_f32_16x16x32_bf16(af[i], bfr[j], acc[i][j], 0, 0, 0);
        __syncthreads();
    }

    #pragma unroll
    for (int i = 0; i < 4; i++) {
        #pragma unroll
        for (int j = 0; j < 4; j++) {
            int col = n0 + wn * 64 + j * 16 + lm;
            if (col >= N) continue;
            float bv = bias ? bias[col] : 0.0f;
            #pragma unroll
            for (int r = 0; r < 4; r++) {
                int row = m0 + wm * 64 + i * 16 + lk * 4 + r;
                if (row >= M) continue;
                float v = acc[i][j][r] + bv;
                if (mode == EP_PLAIN) {
                    ((float*)Cout)[(size_t)row * N + col] = v;
                } else if (mode == EP_VSCAT_BF16) {
                    int bb  = row / NVTOT;
                    int pix = row - bb * NVTOT;
                    int hh  = col >> 5, dc = col & 31;
                    ((__hip_bfloat16*)Cout)[(((size_t)(bb * HEADS + hh)) * NVTOT + pix) * DHEAD + dc]
                        = __float2bfloat16(v);
                } else if (mode == EP_RES) {
                    ((float*)Cout)[(size_t)row * N + col] = v + res[(size_t)row * N + col];
                } else { // EP_GELU_BF16
                    float gl = 0.5f * v * (1.0f + erff(v * 0.70710678118654752f));
                    ((__hip_bfloat16*)Cout)[(size_t)row * N + col] = __float2bfloat16(gl);
                }
            }
        }
    }
}

// ---------------------------------------------------------------- softmax over 12 (per token*head)
__global__ __launch_bounds__(256)
void softmax_k(float* __restrict__ a, int n)
{
    int i = blockIdx.x * 256 + threadIdx.x;
    if (i >= n) return;
    float* p = a + (size_t)i * 12;
    float v[12];
    float m = -1e30f;
    #pragma unroll
    for (int j = 0; j < 12; j++) { v[j] = p[j]; m = fmaxf(m, v[j]); }
    float s = 0.0f;
    #pragma unroll
    for (int j = 0; j < 12; j++) { v[j] = expf(v[j] - m); s += v[j]; }
    float r = 1.0f / s;
    #pragma unroll
    for (int j = 0; j < 12; j++) p[j] = v[j] * r;
}

// ---------------------------------------------------------------- deformable sampling v2
// One wave per token. Phase 1: 96 (head,point) metadata items computed once each
// by distinct lanes -> LDS. Phase 2: lane = (head, 4-ch group), bf16x4 gathers.
__global__ __launch_bounds__(256)
void sample_k(const __hip_bfloat16* __restrict__ v, const float* __restrict__ off,
              const float* __restrict__ attn, const float* __restrict__ ref,
              __hip_bfloat16* __restrict__ out)
{
    // slot index s = wid*104 + h*13 + p  (stride 13 -> conflict-free banks)
    __shared__ int4   metaIdx[4 * 104];
    __shared__ float4 metaW[4 * 104];

    int wid  = threadIdx.x >> 6;
    int lane = threadIdx.x & 63;
    int t    = blockIdx.x * 4 + wid;
    int b    = t >> 14;
    float rx = ref[(size_t)t * 2 + 0];
    float ry = ref[(size_t)t * 2 + 1];

    // ---- phase 1: metadata (2 rounds x 64 lanes = 128 slots, 96 active)
    #pragma unroll
    for (int rnd = 0; rnd < 2; rnd++) {
        int slot = rnd * 64 + lane;
        int h = slot >> 4, p = slot & 15;
        if (p < 12) {
            int l = p >> 2;
            float fS = (l == 0) ? 100.0f : ((l == 1) ? 50.0f : 25.0f);
            int   Wl = (l == 0) ? 100 : ((l == 1) ? 50 : 25);
            int   st = (l == 0) ? 0 : ((l == 1) ? 10000 : 12500);
            float ox = off[(size_t)t * 192 + h * 24 + p * 2 + 0];
            float oy = off[(size_t)t * 192 + h * 24 + p * 2 + 1];
            float aw = attn[(size_t)t * 96 + h * 12 + p];
            float x = (rx + ox / fS) * fS - 0.5f;
            float y = (ry + oy / fS) * fS - 0.5f;
            float x0f = floorf(x), y0f = floorf(y);
            float fx = x - x0f, fy = y - y0f;
            int x0 = (int)x0f, y0 = (int)y0f;
            int x1 = x0 + 1,  y1 = y0 + 1;
            int cx0 = imin(imax(x0, 0), Wl - 1), cx1 = imin(imax(x1, 0), Wl - 1);
            int cy0 = imin(imax(y0, 0), Wl - 1), cy1 = imin(imax(y1, 0), Wl - 1);
            float vx0 = (x0 >= 0 && x0 < Wl) ? 1.0f : 0.0f;
            float vx1 = (x1 >= 0 && x1 < Wl) ? 1.0f : 0.0f;
            float vy0 = (y0 >= 0 && y0 < Wl) ? 1.0f : 0.0f;
            float vy1 = (y1 >= 0 && y1 < Wl) ? 1.0f : 0.0f;
            int s = wid * 104 + h * 13 + p;
            metaIdx[s] = make_int4(st + cy0 * Wl + cx0, st + cy0 * Wl + cx1,
                                   st + cy1 * Wl + cx0, st + cy1 * Wl + cx1);
            metaW[s] = make_float4((1.0f - fx) * (1.0f - fy) * aw * vx0 * vy0,
                                   fx * (1.0f - fy) * aw * vx1 * vy0,
                                   (1.0f - fx) * fy * aw * vx0 * vy1,
                                   fx * fy * aw * vx1 * vy1);
        }
    }
    __syncthreads();

    // ---- phase 2: gather + FMA. lane = h*8 + c8 (c8 = 4-channel group)
    int h  = lane >> 3;
    int c8 = lane & 7;
    const __hip_bfloat16* vbh = v + ((size_t)(b * HEADS + h)) * NVTOT * DHEAD + c8 * 4;
    float4 acc = {0.0f, 0.0f, 0.0f, 0.0f};
    #pragma unroll
    for (int p = 0; p < 12; p++) {
        int s = wid * 104 + h * 13 + p;
        int4   mi = metaIdx[s];
        float4 mw = metaW[s];
        ushort4 r0 = *(const ushort4*)(vbh + (size_t)mi.x * DHEAD);
        ushort4 r1 = *(const ushort4*)(vbh + (size_t)mi.y * DHEAD);
        ushort4 r2 = *(const ushort4*)(vbh + (size_t)mi.z * DHEAD);
        ushort4 r3 = *(const ushort4*)(vbh + (size_t)mi.w * DHEAD);
        acc.x = fmaf(mw.x, __uint_as_float((unsigned)r0.x << 16), acc.x);
        acc.y = fmaf(mw.x, __uint_as_float((unsigned)r0.y << 16), acc.y);
        acc.z = fmaf(mw.x, __uint_as_float((unsigned)r0.z << 16), acc.z);
        acc.w = fmaf(mw.x, __uint_as_float((unsigned)r0.w << 16), acc.w);
        acc.x = fmaf(mw.y, __uint_as_float((unsigned)r1.x << 16), acc.x);
        acc.y = fmaf(mw.y, __uint_as_float((unsigned)r1.y << 16), acc.y);
        acc.z = fmaf(mw.y, __uint_as_float((unsigned)r1.z << 16), acc.z);
        acc.w = fmaf(mw.y, __uint_as_float((unsigned)r1.w << 16), acc.w);
        acc.x = fmaf(mw.z, __uint_as_float((unsigned)r2.x << 16), acc.x);
        acc.y = fmaf(mw.z, __uint_as_float((unsigned)r2.y << 16), acc.y);
        acc.z = fmaf(mw.z, __uint_as_float((unsigned)r2.z << 16), acc.z);
        acc.w = fmaf(mw.z, __uint_as_float((unsigned)r2.w << 16), acc.w);
        acc.x = fmaf(mw.w, __uint_as_float((unsigned)r3.x << 16), acc.x);
        acc.y = fmaf(mw.w, __uint_as_float((unsigned)r3.y << 16), acc.y);
        acc.z = fmaf(mw.w, __uint_as_float((unsigned)r3.z << 16), acc.z);
        acc.w = fmaf(mw.w, __uint_as_float((unsigned)r3.w << 16), acc.w);
    }
    bf16x4 r;
    r.v[0] = __float2bfloat16(acc.x); r.v[1] = __float2bfloat16(acc.y);
    r.v[2] = __float2bfloat16(acc.z); r.v[3] = __float2bfloat16(acc.w);
    *(bf16x4*)(out + (size_t)t * CDIM + h * DHEAD + c8 * 4) = r;
}

// ---------------------------------------------------------------- launch
extern "C" void kernel_launch(void* const* d_in, const int* in_sizes, int n_in,
                              void* d_out, int out_size, void* d_ws, size_t ws_size,
                              hipStream_t stream)
{
    const float* query = (const float*)d_in[0];
    const float* value = (const float*)d_in[1];
    const float* qpos  = (const float*)d_in[2];
    const float* ref   = (const float*)d_in[3];
    const float* ln1g  = (const float*)d_in[6];
    const float* ln1b  = (const float*)d_in[7];
    const float* ln2g  = (const float*)d_in[8];
    const float* ln2b  = (const float*)d_in[9];
    const float* Wv    = (const float*)d_in[10];
    const float* bv    = (const float*)d_in[11];
    const float* Woff  = (const float*)d_in[12];
    const float* boff  = (const float*)d_in[13];
    const float* Wat   = (const float*)d_in[14];
    const float* bat   = (const float*)d_in[15];
    const float* Wout  = (const float*)d_in[16];
    const float* bout  = (const float*)d_in[17];
    const float* W1    = (const float*)d_in[18];
    const float* b1    = (const float*)d_in[19];
    const float* W2    = (const float*)d_in[20];
    const float* b2    = (const float*)d_in[21];
    float* out = (float*)d_out;
    char*  ws  = (char*)d_ws;

    const size_t MB = 1024 * 1024;
    __hip_bfloat16* Wvt   = (__hip_bfloat16*)(ws + 0);
    __hip_bfloat16* Wofft = (__hip_bfloat16*)(ws + 131072);
    __hip_bfloat16* Watt  = (__hip_bfloat16*)(ws + 262144);
    __hip_bfloat16* Woutt = (__hip_bfloat16*)(ws + 327680);
    __hip_bfloat16* W1t   = (__hip_bfloat16*)(ws + 458752);
    __hip_bfloat16* W2t   = (__hip_bfloat16*)(ws + 983040);
    __hip_bfloat16* qbf   = (__hip_bfloat16*)(ws + 2  * MB);  // 16.78 MB; reused as h
    __hip_bfloat16* aoutb = (__hip_bfloat16*)(ws + 19 * MB);  // 16.78 MB
    __hip_bfloat16* vbf   = (__hip_bfloat16*)(ws + 36 * MB);  // 13.44 MB (bf16 value input)
    __hip_bfloat16* vbuf  = (__hip_bfloat16*)(ws + 50 * MB);  // 13.44 MB scattered v (bf16)
    float*          obuf  = (float*)(ws + 77  * MB);          // 25.17 MB offsets
    float*          abuf  = (float*)(ws + 103 * MB);          // 12.58 MB attn
    __hip_bfloat16* gbf   = (__hip_bfloat16*)(ws + 50 * MB);  // 67.1 MB, aliases vbuf/obuf/abuf
    __hip_bfloat16* hbf   = qbf;

    // 0. all weights -> bf16 transposed [Npad][K] (one launch)
    wt_all_k<<<2944, 256, 0, stream>>>(Wv, Woff, Wat, Wout, W1, W2,
                                       Wvt, Wofft, Watt, Woutt, W1t, W2t);
    // 0b. value -> bf16
    cvt_k<<<(MROWS_V * CDIM / 4 + 255) / 256, 256, 0, stream>>>(value, vbf, MROWS_V * CDIM / 4);
    // 1. q = LN1(query) + query_pos  (bf16)
    ln_bf16_k<<<NTOK / 4, 256, 0, stream>>>(query, qpos, ln1g, ln1b, qbf);
    // 2. v = value @ W_value + b_value, scattered [b][h][pix][d] bf16
    mm_k<<<dim3(2, (MROWS_V + 127) / 128), 256, 0, stream>>>(
        vbf, Wvt, bv, nullptr, vbuf, MROWS_V, 256, 256, EP_VSCAT_BF16);
    // 3. offsets = q @ W_off + b_off  (fp32)
    mm_k<<<dim3(2, NTOK / 128), 256, 0, stream>>>(
        qbf, Wofft, boff, nullptr, obuf, NTOK, 192, 256, EP_PLAIN);
    // 4. attn logits = q @ W_attn + b_attn  (fp32)
    mm_k<<<dim3(1, NTOK / 128), 256, 0, stream>>>(
        qbf, Watt, bat, nullptr, abuf, NTOK, 96, 256, EP_PLAIN);
    // 5. softmax over 12
    softmax_k<<<(NTOK * HEADS) / 256, 256, 0, stream>>>(abuf, NTOK * HEADS);
    // 6. sampling -> aout bf16  (one wave per token)
    sample_k<<<NTOK / 4, 256, 0, stream>>>(vbuf, obuf, abuf, ref, aoutb);
    // 7. x = query + aout @ W_out + b_out -> d_out fp32
    mm_k<<<dim3(2, NTOK / 128), 256, 0, stream>>>(
        aoutb, Woutt, bout, query, out, NTOK, 256, 256, EP_RES);
    // 8. h = LN2(x)  bf16
    ln_bf16_k<<<NTOK / 4, 256, 0, stream>>>(out, nullptr, ln2g, ln2b, hbf);
    // 9. g = gelu(h @ W_ffn1 + b_ffn1)  bf16
    mm_k<<<dim3(8, NTOK / 128), 256, 0, stream>>>(
        hbf, W1t, b1, nullptr, gbf, NTOK, FDIM, 256, EP_GELU_BF16);
    // 10. out = x + g @ W_ffn2 + b_ffn2  (in-place residual)
    mm_k<<<dim3(2, NTOK / 128), 256, 0, stream>>>(
        gbf, W2t, b2, out, out, NTOK, 256, FDIM, EP_RES);
}

// Round 4
// 474.850 us; speedup vs baseline: 2.5560x; 1.0565x over previous
//
#include <hip/hip_runtime.h>
#include <hip/hip_bf16.h>

// Problem constants (fixed by setup_inputs)
#define BQ      2
#define QLEN    16384            // 128*128
#define CDIM    256
#define HEADS   8
#define LEV     3
#define PTS     4
#define DHEAD   32
#define NVTOT   13125            // 100*100 + 50*50 + 25*25
#define FDIM    1024
#define NTOK    (BQ*QLEN)        // 32768
#define MROWS_V (BQ*NVTOT)       // 26250
#define NPROJ   288              // 192 offsets + 96 attn logits, fused

typedef __attribute__((ext_vector_type(8))) short short8;     // 8 bf16 = 4 VGPRs
typedef __attribute__((ext_vector_type(4))) float floatx4;    // MFMA acc

typedef const __attribute__((address_space(1))) unsigned int gu32;
typedef __attribute__((address_space(3))) unsigned int lu32;

struct bf16x4 { __hip_bfloat16 v[4]; };

__device__ __forceinline__ int imin(int a, int b){ return a<b?a:b; }
__device__ __forceinline__ int imax(int a, int b){ return a>b?a:b; }

// ---------------------------------------------------------------- LayerNorm (+optional pos add), bf16 out
__global__ __launch_bounds__(256)
void ln_bf16_k(const float* __restrict__ x, const float* __restrict__ pos,
               const float* __restrict__ g, const float* __restrict__ b,
               __hip_bfloat16* __restrict__ out)
{
    int tok  = blockIdx.x * 4 + (threadIdx.x >> 6);
    int lane = threadIdx.x & 63;
    float4 v = ((const float4*)(x + (size_t)tok * CDIM))[lane];
    float s = v.x + v.y + v.z + v.w;
    #pragma unroll
    for (int o = 32; o > 0; o >>= 1) s += __shfl_down(s, o);
    s = __shfl(s, 0);
    float mean = s * (1.0f / 256.0f);
    float4 c; c.x = v.x - mean; c.y = v.y - mean; c.z = v.z - mean; c.w = v.w - mean;
    float q2 = c.x*c.x + c.y*c.y + c.z*c.z + c.w*c.w;
    #pragma unroll
    for (int o = 32; o > 0; o >>= 1) q2 += __shfl_down(q2, o);
    q2 = __shfl(q2, 0);
    float rstd = rsqrtf(q2 * (1.0f / 256.0f) + 1e-5f);
    float4 gg = ((const float4*)g)[lane];
    float4 bb = ((const float4*)b)[lane];
    float4 o4;
    o4.x = c.x * rstd * gg.x + bb.x;
    o4.y = c.y * rstd * gg.y + bb.y;
    o4.z = c.z * rstd * gg.z + bb.z;
    o4.w = c.w * rstd * gg.w + bb.w;
    if (pos) {
        float4 p = ((const float4*)(pos + (size_t)tok * CDIM))[lane];
        o4.x += p.x; o4.y += p.y; o4.z += p.z; o4.w += p.w;
    }
    bf16x4 r;
    r.v[0] = __float2bfloat16(o4.x); r.v[1] = __float2bfloat16(o4.y);
    r.v[2] = __float2bfloat16(o4.z); r.v[3] = __float2bfloat16(o4.w);
    ((bf16x4*)(out + (size_t)tok * CDIM))[lane] = r;
}

// ---------------------------------------------------------------- fp32 -> bf16 convert
__global__ __launch_bounds__(256)
void cvt_k(const float* __restrict__ in, __hip_bfloat16* __restrict__ out, int n4)
{
    int i = blockIdx.x * 256 + threadIdx.x;
    if (i >= n4) return;
    float4 v = ((const float4*)in)[i];
    bf16x4 r;
    r.v[0] = __float2bfloat16(v.x); r.v[1] = __float2bfloat16(v.y);
    r.v[2] = __float2bfloat16(v.z); r.v[3] = __float2bfloat16(v.w);
    ((bf16x4*)out)[i] = r;
}

// ---------------------------------------------------------------- fused weight transpose+convert (+combined proj weight & bias)
// W[K][N] fp32 -> Wt[Npad][K] bf16. Woff+Wat fused into one [384][256] (zero-pad).
__global__ __launch_bounds__(256)
void wt_all_k(const float* __restrict__ Wv,  const float* __restrict__ Woff,
              const float* __restrict__ Wat, const float* __restrict__ Wout,
              const float* __restrict__ W1,  const float* __restrict__ W2,
              const float* __restrict__ boff, const float* __restrict__ bat,
              __hip_bfloat16* __restrict__ o_v,  __hip_bfloat16* __restrict__ o_c,
              __hip_bfloat16* __restrict__ o_out,
              __hip_bfloat16* __restrict__ o_1,  __hip_bfloat16* __restrict__ o_2,
              float* __restrict__ o_bc)
{
    int gid = blockIdx.x * 256 + threadIdx.x;
    if (gid < 65536) {                      // Wv  [256][256] -> [256][256]
        int idx = gid, n = idx >> 8, k = idx & 255;
        o_v[idx] = __float2bfloat16(Wv[(size_t)k * 256 + n]);
    } else if (gid < 163840) {              // combined proj -> [384][256]
        int idx = gid - 65536, n = idx >> 8, k = idx & 255;
        float v = 0.0f;
        if (n < 192)       v = Woff[(size_t)k * 192 + n];
        else if (n < 288)  v = Wat[(size_t)k * 96 + (n - 192)];
        o_c[idx] = __float2bfloat16(v);
    } else if (gid < 229376) {              // Wout [256][256]
        int idx = gid - 163840, n = idx >> 8, k = idx & 255;
        o_out[idx] = __float2bfloat16(Wout[(size_t)k * 256 + n]);
    } else if (gid < 491520) {              // W1 [256][1024] -> [1024][256]
        int idx = gid - 229376, n = idx >> 8, k = idx & 255;
        o_1[idx] = __float2bfloat16(W1[(size_t)k * 1024 + n]);
    } else if (gid < 753664) {              // W2 [1024][256] -> [256][1024]
        int idx = gid - 491520, n = idx >> 10, k = idx & 1023;
        o_2[idx] = __float2bfloat16(W2[(size_t)k * 256 + n]);
    } else if (gid < 753952) {              // combined bias [288]
        int idx = gid - 753664;
        o_bc[idx] = (idx < 192) ? boff[idx] : bat[idx - 192];
    }
}

// ---------------------------------------------------------------- bf16 MFMA GEMM (m97 structure)
// grid = (rowTiles, colTiles): same-A-row blocks differ by rowTiles (mult of 8)
// in flat id -> same XCD -> A tile L2-local.
enum { EP_PLAIN = 0, EP_VSCAT_BF16 = 1, EP_RES = 2, EP_GELU_BF16 = 3 };

__global__ __launch_bounds__(256)
void mm_k(const __hip_bfloat16* __restrict__ A, const __hip_bfloat16* __restrict__ Bt,
          const float* __restrict__ bias, const float* __restrict__ res,
          void* __restrict__ Cout, int M, int N, int K, int mode)
{
    __shared__ __hip_bfloat16 As[128 * 32];
    __shared__ __hip_bfloat16 Bs[128 * 32];
    int t = threadIdx.x;
    int lane = t & 63;
    int wave = t >> 6;
    int wm = wave >> 1, wn = wave & 1;
    int lm = lane & 15, lk = lane >> 4;
    int m0 = blockIdx.x * 128;     // row tiles on x: XCD-local A reuse
    int n0 = blockIdx.y * 128;

    floatx4 acc[4][4];
    #pragma unroll
    for (int i = 0; i < 4; i++)
        #pragma unroll
        for (int j = 0; j < 4; j++) acc[i][j] = (floatx4)0.0f;

    for (int kt = 0; kt < K; kt += 32) {
        #pragma unroll
        for (int i = 0; i < 2; i++) {
            int cc  = i * 256 + t;
            int row = cc >> 2;
            int ko  = (cc & 3) * 8;
            int ra  = m0 + row; if (ra >= M) ra = M - 1;
            const __hip_bfloat16* ga = A  + (size_t)ra * K + kt + ko;
            const __hip_bfloat16* gb = Bt + (size_t)(n0 + row) * K + kt + ko;
            __builtin_amdgcn_global_load_lds((gu32*)ga, (lu32*)(As + cc * 8), 16, 0, 0);
            __builtin_amdgcn_global_load_lds((gu32*)gb, (lu32*)(Bs + cc * 8), 16, 0, 0);
        }
        __syncthreads();
        short8 af[4], bfr[4];
        #pragma unroll
        for (int i = 0; i < 4; i++) {
            af[i]  = *(const short8*)(As + (wm * 64 + i * 16 + lm) * 32 + lk * 8);
            bfr[i] = *(const short8*)(Bs + (wn * 64 + i * 16 + lm) * 32 + lk * 8);
        }
        #pragma unroll
        for (int i = 0; i < 4; i++)
            #pragma unroll
            for (int j = 0; j < 4; j++)
                acc[i][j] = __builtin_amdgcn_mfma_f32_16x16x32_bf16(af[i], bfr[j], acc[i][j], 0, 0, 0);
        __syncthreads();
    }

    #pragma unroll
    for (int i = 0; i < 4; i++) {
        #pragma unroll
        for (int j = 0; j < 4; j++) {
            int col = n0 + wn * 64 + j * 16 + lm;
            if (col >= N) continue;
            float bv = bias ? bias[col] : 0.0f;
            #pragma unroll
            for (int r = 0; r < 4; r++) {
                int row = m0 + wm * 64 + i * 16 + lk * 4 + r;
                if (row >= M) continue;
                float v = acc[i][j][r] + bv;
                if (mode == EP_PLAIN) {
                    ((float*)Cout)[(size_t)row * N + col] = v;
                } else if (mode == EP_VSCAT_BF16) {
                    int bb  = row / NVTOT;
                    int pix = row - bb * NVTOT;
                    int hh  = col >> 5, dc = col & 31;
                    ((__hip_bfloat16*)Cout)[(((size_t)(bb * HEADS + hh)) * NVTOT + pix) * DHEAD + dc]
                        = __float2bfloat16(v);
                } else if (mode == EP_RES) {
                    ((float*)Cout)[(size_t)row * N + col] = v + res[(size_t)row * N + col];
                } else { // EP_GELU_BF16
                    float gl = 0.5f * v * (1.0f + erff(v * 0.70710678118654752f));
                    ((__hip_bfloat16*)Cout)[(size_t)row * N + col] = __float2bfloat16(gl);
                }
            }
        }
    }
}

// ---------------------------------------------------------------- deformable sampling v3
// One wave per token. Phase 1: 96 (head,point) metadata items computed once each,
// with softmax over 12 done inline via width-16 shuffles. Phase 2: bf16x4 gathers.
// cbuf layout per token (stride 288): [0..191] offsets, [192..287] attn logits.
__global__ __launch_bounds__(256)
void sample_k(const __hip_bfloat16* __restrict__ v, const float* __restrict__ cbuf,
              const float* __restrict__ ref, __hip_bfloat16* __restrict__ out)
{
    __shared__ int4   metaIdx[4 * 104];   // stride 13 slots -> conflict-free
    __shared__ float4 metaW[4 * 104];

    int wid  = threadIdx.x >> 6;
    int lane = threadIdx.x & 63;
    int t    = blockIdx.x * 4 + wid;
    int b    = t >> 14;
    float rx = ref[(size_t)t * 2 + 0];
    float ry = ref[(size_t)t * 2 + 1];
    const float* crow = cbuf + (size_t)t * NPROJ;

    #pragma unroll
    for (int rnd = 0; rnd < 2; rnd++) {
        int slot = rnd * 64 + lane;
        int h = slot >> 4, p = slot & 15;
        int pc = imin(p, 11);
        float2 oxy  = *(const float2*)(crow + h * 24 + pc * 2);
        float logit = crow[192 + h * 12 + pc];
        // softmax over the 12 points of this head (lanes h*16..h*16+11)
        float mx = logit;
        #pragma unroll
        for (int o = 8; o > 0; o >>= 1) mx = fmaxf(mx, __shfl_xor(mx, o, 16));
        float e = (p < 12) ? __expf(logit - mx) : 0.0f;
        float ssum = e;
        #pragma unroll
        for (int o = 8; o > 0; o >>= 1) ssum += __shfl_xor(ssum, o, 16);
        float aw = e / ssum;

        if (p < 12) {
            int l = p >> 2;
            float fS = (l == 0) ? 100.0f : ((l == 1) ? 50.0f : 25.0f);
            int   Wl = (l == 0) ? 100 : ((l == 1) ? 50 : 25);
            int   st = (l == 0) ? 0 : ((l == 1) ? 10000 : 12500);
            float x = (rx + oxy.x / fS) * fS - 0.5f;
            float y = (ry + oxy.y / fS) * fS - 0.5f;
            float x0f = floorf(x), y0f = floorf(y);
            float fx = x - x0f, fy = y - y0f;
            int x0 = (int)x0f, y0 = (int)y0f;
            int x1 = x0 + 1,  y1 = y0 + 1;
            int cx0 = imin(imax(x0, 0), Wl - 1), cx1 = imin(imax(x1, 0), Wl - 1);
            int cy0 = imin(imax(y0, 0), Wl - 1), cy1 = imin(imax(y1, 0), Wl - 1);
            float vx0 = (x0 >= 0 && x0 < Wl) ? 1.0f : 0.0f;
            float vx1 = (x1 >= 0 && x1 < Wl) ? 1.0f : 0.0f;
            float vy0 = (y0 >= 0 && y0 < Wl) ? 1.0f : 0.0f;
            float vy1 = (y1 >= 0 && y1 < Wl) ? 1.0f : 0.0f;
            int s = wid * 104 + h * 13 + p;
            metaIdx[s] = make_int4(st + cy0 * Wl + cx0, st + cy0 * Wl + cx1,
                                   st + cy1 * Wl + cx0, st + cy1 * Wl + cx1);
            metaW[s] = make_float4((1.0f - fx) * (1.0f - fy) * aw * vx0 * vy0,
                                   fx * (1.0f - fy) * aw * vx1 * vy0,
                                   (1.0f - fx) * fy * aw * vx0 * vy1,
                                   fx * fy * aw * vx1 * vy1);
        }
    }
    __syncthreads();

    int h  = lane >> 3;
    int c8 = lane & 7;
    const __hip_bfloat16* vbh = v + ((size_t)(b * HEADS + h)) * NVTOT * DHEAD + c8 * 4;
    float4 acc = {0.0f, 0.0f, 0.0f, 0.0f};
    #pragma unroll
    for (int p = 0; p < 12; p++) {
        int s = wid * 104 + h * 13 + p;
        int4   mi = metaIdx[s];
        float4 mw = metaW[s];
        ushort4 r0 = *(const ushort4*)(vbh + (size_t)mi.x * DHEAD);
        ushort4 r1 = *(const ushort4*)(vbh + (size_t)mi.y * DHEAD);
        ushort4 r2 = *(const ushort4*)(vbh + (size_t)mi.z * DHEAD);
        ushort4 r3 = *(const ushort4*)(vbh + (size_t)mi.w * DHEAD);
        acc.x = fmaf(mw.x, __uint_as_float((unsigned)r0.x << 16), acc.x);
        acc.y = fmaf(mw.x, __uint_as_float((unsigned)r0.y << 16), acc.y);
        acc.z = fmaf(mw.x, __uint_as_float((unsigned)r0.z << 16), acc.z);
        acc.w = fmaf(mw.x, __uint_as_float((unsigned)r0.w << 16), acc.w);
        acc.x = fmaf(mw.y, __uint_as_float((unsigned)r1.x << 16), acc.x);
        acc.y = fmaf(mw.y, __uint_as_float((unsigned)r1.y << 16), acc.y);
        acc.z = fmaf(mw.y, __uint_as_float((unsigned)r1.z << 16), acc.z);
        acc.w = fmaf(mw.y, __uint_as_float((unsigned)r1.w << 16), acc.w);
        acc.x = fmaf(mw.z, __uint_as_float((unsigned)r2.x << 16), acc.x);
        acc.y = fmaf(mw.z, __uint_as_float((unsigned)r2.y << 16), acc.y);
        acc.z = fmaf(mw.z, __uint_as_float((unsigned)r2.z << 16), acc.z);
        acc.w = fmaf(mw.z, __uint_as_float((unsigned)r2.w << 16), acc.w);
        acc.x = fmaf(mw.w, __uint_as_float((unsigned)r3.x << 16), acc.x);
        acc.y = fmaf(mw.w, __uint_as_float((unsigned)r3.y << 16), acc.y);
        acc.z = fmaf(mw.w, __uint_as_float((unsigned)r3.z << 16), acc.z);
        acc.w = fmaf(mw.w, __uint_as_float((unsigned)r3.w << 16), acc.w);
    }
    bf16x4 r;
    r.v[0] = __float2bfloat16(acc.x); r.v[1] = __float2bfloat16(acc.y);
    r.v[2] = __float2bfloat16(acc.z); r.v[3] = __float2bfloat16(acc.w);
    *(bf16x4*)(out + (size_t)t * CDIM + h * DHEAD + c8 * 4) = r;
}

// ---------------------------------------------------------------- launch
extern "C" void kernel_launch(void* const* d_in, const int* in_sizes, int n_in,
                              void* d_out, int out_size, void* d_ws, size_t ws_size,
                              hipStream_t stream)
{
    const float* query = (const float*)d_in[0];
    const float* value = (const float*)d_in[1];
    const float* qpos  = (const float*)d_in[2];
    const float* ref   = (const float*)d_in[3];
    const float* ln1g  = (const float*)d_in[6];
    const float* ln1b  = (const float*)d_in[7];
    const float* ln2g  = (const float*)d_in[8];
    const float* ln2b  = (const float*)d_in[9];
    const float* Wv    = (const float*)d_in[10];
    const float* bv    = (const float*)d_in[11];
    const float* Woff  = (const float*)d_in[12];
    const float* boff  = (const float*)d_in[13];
    const float* Wat   = (const float*)d_in[14];
    const float* bat   = (const float*)d_in[15];
    const float* Wout  = (const float*)d_in[16];
    const float* bout  = (const float*)d_in[17];
    const float* W1    = (const float*)d_in[18];
    const float* b1    = (const float*)d_in[19];
    const float* W2    = (const float*)d_in[20];
    const float* b2    = (const float*)d_in[21];
    float* out = (float*)d_out;
    char*  ws  = (char*)d_ws;

    const size_t MB = 1024 * 1024;
    __hip_bfloat16* Wvt   = (__hip_bfloat16*)(ws + 0);        // 256*256
    __hip_bfloat16* Wct   = (__hip_bfloat16*)(ws + 131072);   // 384*256 combined proj
    __hip_bfloat16* Woutt = (__hip_bfloat16*)(ws + 327680);   // 256*256
    __hip_bfloat16* W1t   = (__hip_bfloat16*)(ws + 458752);   // 1024*256
    __hip_bfloat16* W2t   = (__hip_bfloat16*)(ws + 983040);   // 256*1024
    float*          bcomb = (float*)(ws + 1507328);           // 288 floats
    __hip_bfloat16* qbf   = (__hip_bfloat16*)(ws + 2  * MB);  // 16.78 MB; reused as h
    __hip_bfloat16* aoutb = (__hip_bfloat16*)(ws + 19 * MB);  // 16.78 MB
    __hip_bfloat16* vbf   = (__hip_bfloat16*)(ws + 36 * MB);  // 13.44 MB (bf16 value input)
    __hip_bfloat16* vbuf  = (__hip_bfloat16*)(ws + 50 * MB);  // 13.44 MB scattered v (bf16)
    float*          cbuf  = (float*)(ws + 77 * MB);           // 37.75 MB fused proj (stride 288)
    __hip_bfloat16* gbf   = (__hip_bfloat16*)(ws + 50 * MB);  // 67.1 MB, aliases vbuf/cbuf (dead by step 9)
    __hip_bfloat16* hbf   = qbf;

    // 0. weights -> bf16 transposed (+ combined proj weight/bias), one launch
    wt_all_k<<<2946, 256, 0, stream>>>(Wv, Woff, Wat, Wout, W1, W2, boff, bat,
                                       Wvt, Wct, Woutt, W1t, W2t, bcomb);
    // 0b. value -> bf16
    cvt_k<<<(MROWS_V * CDIM / 4 + 255) / 256, 256, 0, stream>>>(value, vbf, MROWS_V * CDIM / 4);
    // 1. q = LN1(query) + query_pos  (bf16)
    ln_bf16_k<<<NTOK / 4, 256, 0, stream>>>(query, qpos, ln1g, ln1b, qbf);
    // 2. v = value @ W_value + b_value, scattered [b][h][pix][d] bf16
    mm_k<<<dim3((MROWS_V + 127) / 128, 2), 256, 0, stream>>>(
        vbf, Wvt, bv, nullptr, vbuf, MROWS_V, 256, 256, EP_VSCAT_BF16);
    // 3. fused proj: [offsets | attn logits] = q @ [W_off|W_attn] + [b_off|b_attn]
    mm_k<<<dim3(NTOK / 128, 3), 256, 0, stream>>>(
        qbf, Wct, bcomb, nullptr, cbuf, NTOK, NPROJ, 256, EP_PLAIN);
    // 4. sampling (inline softmax) -> aout bf16
    sample_k<<<NTOK / 4, 256, 0, stream>>>(vbuf, cbuf, ref, aoutb);
    // 5. x = query + aout @ W_out + b_out -> d_out fp32
    mm_k<<<dim3(NTOK / 128, 2), 256, 0, stream>>>(
        aoutb, Woutt, bout, query, out, NTOK, 256, 256, EP_RES);
    // 6. h = LN2(x)  bf16
    ln_bf16_k<<<NTOK / 4, 256, 0, stream>>>(out, nullptr, ln2g, ln2b, hbf);
    // 7. g = gelu(h @ W_ffn1 + b_ffn1)  bf16
    mm_k<<<dim3(NTOK / 128, 8), 256, 0, stream>>>(
        hbf, W1t, b1, nullptr, gbf, NTOK, FDIM, 256, EP_GELU_BF16);
    // 8. out = x + g @ W_ffn2 + b_ffn2  (in-place residual)
    mm_k<<<dim3(NTOK / 128, 2), 256, 0, stream>>>(
        gbf, W2t, b2, out, out, NTOK, 256, FDIM, EP_RES);
}

// Round 5
// 458.477 us; speedup vs baseline: 2.6473x; 1.0357x over previous
//
#include <hip/hip_runtime.h>
#include <hip/hip_bf16.h>

// Problem constants (fixed by setup_inputs)
#define BQ      2
#define QLEN    16384            // 128*128
#define CDIM    256
#define HEADS   8
#define LEV     3
#define PTS     4
#define DHEAD   32
#define NVTOT   13125            // 100*100 + 50*50 + 25*25
#define FDIM    1024
#define NTOK    (BQ*QLEN)        // 32768
#define MROWS_V (BQ*NVTOT)       // 26250
#define NPROJ   288              // 192 offsets + 96 attn logits, fused

typedef __attribute__((ext_vector_type(8))) short short8;     // 8 bf16 = 4 VGPRs
typedef __attribute__((ext_vector_type(4))) float floatx4;    // MFMA acc

typedef const __attribute__((address_space(1))) unsigned int gu32;
typedef __attribute__((address_space(3))) unsigned int lu32;

struct bf16x4 { __hip_bfloat16 v[4]; };

__device__ __forceinline__ int imin(int a, int b){ return a<b?a:b; }
__device__ __forceinline__ int imax(int a, int b){ return a>b?a:b; }

// saturation-safe fast gelu (tanh form); error vs exact erf-gelu ~3e-4,
// below bf16 output rounding.
__device__ __forceinline__ float gelu_f(float x)
{
    float u = 0.7978845608028654f * (x + 0.044715f * x * x * x);
    float e = __expf(2.0f * u);
    float th = 1.0f - 2.0f / (e + 1.0f);   // e->inf: 1, e->0: -1 (no NaN)
    return 0.5f * x * (1.0f + th);
}

// ---------------------------------------------------------------- LayerNorm (+optional pos add), bf16 out
__global__ __launch_bounds__(256)
void ln_bf16_k(const float* __restrict__ x, const float* __restrict__ pos,
               const float* __restrict__ g, const float* __restrict__ b,
               __hip_bfloat16* __restrict__ out)
{
    int tok  = blockIdx.x * 4 + (threadIdx.x >> 6);
    int lane = threadIdx.x & 63;
    float4 v = ((const float4*)(x + (size_t)tok * CDIM))[lane];
    float s = v.x + v.y + v.z + v.w;
    #pragma unroll
    for (int o = 32; o > 0; o >>= 1) s += __shfl_down(s, o);
    s = __shfl(s, 0);
    float mean = s * (1.0f / 256.0f);
    float4 c; c.x = v.x - mean; c.y = v.y - mean; c.z = v.z - mean; c.w = v.w - mean;
    float q2 = c.x*c.x + c.y*c.y + c.z*c.z + c.w*c.w;
    #pragma unroll
    for (int o = 32; o > 0; o >>= 1) q2 += __shfl_down(q2, o);
    q2 = __shfl(q2, 0);
    float rstd = rsqrtf(q2 * (1.0f / 256.0f) + 1e-5f);
    float4 gg = ((const float4*)g)[lane];
    float4 bb = ((const float4*)b)[lane];
    float4 o4;
    o4.x = c.x * rstd * gg.x + bb.x;
    o4.y = c.y * rstd * gg.y + bb.y;
    o4.z = c.z * rstd * gg.z + bb.z;
    o4.w = c.w * rstd * gg.w + bb.w;
    if (pos) {
        float4 p = ((const float4*)(pos + (size_t)tok * CDIM))[lane];
        o4.x += p.x; o4.y += p.y; o4.z += p.z; o4.w += p.w;
    }
    bf16x4 r;
    r.v[0] = __float2bfloat16(o4.x); r.v[1] = __float2bfloat16(o4.y);
    r.v[2] = __float2bfloat16(o4.z); r.v[3] = __float2bfloat16(o4.w);
    ((bf16x4*)(out + (size_t)tok * CDIM))[lane] = r;
}

// ---------------------------------------------------------------- fp32 -> bf16 convert
__global__ __launch_bounds__(256)
void cvt_k(const float* __restrict__ in, __hip_bfloat16* __restrict__ out, int n4)
{
    int i = blockIdx.x * 256 + threadIdx.x;
    if (i >= n4) return;
    float4 v = ((const float4*)in)[i];
    bf16x4 r;
    r.v[0] = __float2bfloat16(v.x); r.v[1] = __float2bfloat16(v.y);
    r.v[2] = __float2bfloat16(v.z); r.v[3] = __float2bfloat16(v.w);
    ((bf16x4*)out)[i] = r;
}

// ---------------------------------------------------------------- fused weight transpose+convert (+combined proj weight & bias)
__global__ __launch_bounds__(256)
void wt_all_k(const float* __restrict__ Wv,  const float* __restrict__ Woff,
              const float* __restrict__ Wat, const float* __restrict__ Wout,
              const float* __restrict__ W1,  const float* __restrict__ W2,
              const float* __restrict__ boff, const float* __restrict__ bat,
              __hip_bfloat16* __restrict__ o_v,  __hip_bfloat16* __restrict__ o_c,
              __hip_bfloat16* __restrict__ o_out,
              __hip_bfloat16* __restrict__ o_1,  __hip_bfloat16* __restrict__ o_2,
              float* __restrict__ o_bc)
{
    int gid = blockIdx.x * 256 + threadIdx.x;
    if (gid < 65536) {                      // Wv  [256][256] -> [256][256]
        int idx = gid, n = idx >> 8, k = idx & 255;
        o_v[idx] = __float2bfloat16(Wv[(size_t)k * 256 + n]);
    } else if (gid < 163840) {              // combined proj -> [384][256]
        int idx = gid - 65536, n = idx >> 8, k = idx & 255;
        float v = 0.0f;
        if (n < 192)       v = Woff[(size_t)k * 192 + n];
        else if (n < 288)  v = Wat[(size_t)k * 96 + (n - 192)];
        o_c[idx] = __float2bfloat16(v);
    } else if (gid < 229376) {              // Wout [256][256]
        int idx = gid - 163840, n = idx >> 8, k = idx & 255;
        o_out[idx] = __float2bfloat16(Wout[(size_t)k * 256 + n]);
    } else if (gid < 491520) {              // W1 [256][1024] -> [1024][256]
        int idx = gid - 229376, n = idx >> 8, k = idx & 255;
        o_1[idx] = __float2bfloat16(W1[(size_t)k * 1024 + n]);
    } else if (gid < 753664) {              // W2 [1024][256] -> [256][1024]
        int idx = gid - 491520, n = idx >> 10, k = idx & 1023;
        o_2[idx] = __float2bfloat16(W2[(size_t)k * 256 + n]);
    } else if (gid < 753952) {              // combined bias [288]
        int idx = gid - 753664;
        o_bc[idx] = (idx < 192) ? boff[idx] : bat[idx - 192];
    }
}

// ---------------------------------------------------------------- bf16 MFMA GEMM
// BK=64, XOR-swizzled LDS (bank-conflict-free ds_read_b128), grid=(rowTiles,colTiles)
// so same-A-row blocks land on the same XCD.
// LDS layout: 16B chunk for (row, kchunk kc) stored at chunk index row*8 + (kc ^ (row&7)).
enum { EP_PLAIN = 0, EP_VSCAT_BF16 = 1, EP_RES = 2, EP_GELU_BF16 = 3 };

__global__ __launch_bounds__(256)
void mm_k(const __hip_bfloat16* __restrict__ A, const __hip_bfloat16* __restrict__ Bt,
          const float* __restrict__ bias, const float* __restrict__ res,
          void* __restrict__ Cout, int M, int N, int K, int mode)
{
    __shared__ __hip_bfloat16 As[128 * 64];
    __shared__ __hip_bfloat16 Bs[128 * 64];
    int t = threadIdx.x;
    int lane = t & 63;
    int wave = t >> 6;
    int wm = wave >> 1, wn = wave & 1;
    int lm = lane & 15, lk = lane >> 4;
    int m0 = blockIdx.x * 128;
    int n0 = blockIdx.y * 128;

    floatx4 acc[4][4];
    #pragma unroll
    for (int i = 0; i < 4; i++)
        #pragma unroll
        for (int j = 0; j < 4; j++) acc[i][j] = (floatx4)0.0f;

    for (int kt = 0; kt < K; kt += 64) {
        #pragma unroll
        for (int i = 0; i < 4; i++) {
            int cc  = i * 256 + t;          // LDS chunk 0..1023 (16 B each)
            int row = cc >> 3;              // 0..127
            int c   = cc & 7;
            int kc  = c ^ (row & 7);        // global k-chunk this slot holds
            int ra  = m0 + row; if (ra >= M) ra = M - 1;
            const __hip_bfloat16* ga = A  + (size_t)ra * K + kt + kc * 8;
            const __hip_bfloat16* gb = Bt + (size_t)(n0 + row) * K + kt + kc * 8;
            __builtin_amdgcn_global_load_lds((gu32*)ga, (lu32*)(As + cc * 8), 16, 0, 0);
            __builtin_amdgcn_global_load_lds((gu32*)gb, (lu32*)(Bs + cc * 8), 16, 0, 0);
        }
        __syncthreads();
        #pragma unroll
        for (int ks = 0; ks < 2; ks++) {
            short8 af[4], bfr[4];
            #pragma unroll
            for (int i = 0; i < 4; i++) {
                int ra = wm * 64 + i * 16 + lm;
                int ca = (ks * 4 + lk) ^ (ra & 7);
                af[i]  = *(const short8*)(As + (ra * 8 + ca) * 8);
                int rb = wn * 64 + i * 16 + lm;
                int cb = (ks * 4 + lk) ^ (rb & 7);
                bfr[i] = *(const short8*)(Bs + (rb * 8 + cb) * 8);
            }
            #pragma unroll
            for (int i = 0; i < 4; i++)
                #pragma unroll
                for (int j = 0; j < 4; j++)
                    acc[i][j] = __builtin_amdgcn_mfma_f32_16x16x32_bf16(af[i], bfr[j], acc[i][j], 0, 0, 0);
        }
        __syncthreads();
    }

    #pragma unroll
    for (int i = 0; i < 4; i++) {
        #pragma unroll
        for (int j = 0; j < 4; j++) {
            int col = n0 + wn * 64 + j * 16 + lm;
            if (col >= N) continue;
            float bv = bias ? bias[col] : 0.0f;
            #pragma unroll
            for (int r = 0; r < 4; r++) {
                int row = m0 + wm * 64 + i * 16 + lk * 4 + r;
                if (row >= M) continue;
                float v = acc[i][j][r] + bv;
                if (mode == EP_PLAIN) {
                    ((float*)Cout)[(size_t)row * N + col] = v;
                } else if (mode == EP_VSCAT_BF16) {
                    int bb  = row / NVTOT;
                    int pix = row - bb * NVTOT;
                    int hh  = col >> 5, dc = col & 31;
                    ((__hip_bfloat16*)Cout)[(((size_t)(bb * HEADS + hh)) * NVTOT + pix) * DHEAD + dc]
                        = __float2bfloat16(v);
                } else if (mode == EP_RES) {
                    ((float*)Cout)[(size_t)row * N + col] = v + res[(size_t)row * N + col];
                } else { // EP_GELU_BF16
                    ((__hip_bfloat16*)Cout)[(size_t)row * N + col] = __float2bfloat16(gelu_f(v));
                }
            }
        }
    }
}

// ---------------------------------------------------------------- deformable sampling (inline softmax)
__global__ __launch_bounds__(256)
void sample_k(const __hip_bfloat16* __restrict__ v, const float* __restrict__ cbuf,
              const float* __restrict__ ref, __hip_bfloat16* __restrict__ out)
{
    __shared__ int4   metaIdx[4 * 104];   // stride 13 slots -> conflict-free
    __shared__ float4 metaW[4 * 104];

    int wid  = threadIdx.x >> 6;
    int lane = threadIdx.x & 63;
    int t    = blockIdx.x * 4 + wid;
    int b    = t >> 14;
    float rx = ref[(size_t)t * 2 + 0];
    float ry = ref[(size_t)t * 2 + 1];
    const float* crow = cbuf + (size_t)t * NPROJ;

    #pragma unroll
    for (int rnd = 0; rnd < 2; rnd++) {
        int slot = rnd * 64 + lane;
        int h = slot >> 4, p = slot & 15;
        int pc = imin(p, 11);
        float2 oxy  = *(const float2*)(crow + h * 24 + pc * 2);
        float logit = crow[192 + h * 12 + pc];
        float mx = logit;
        #pragma unroll
        for (int o = 8; o > 0; o >>= 1) mx = fmaxf(mx, __shfl_xor(mx, o, 16));
        float e = (p < 12) ? __expf(logit - mx) : 0.0f;
        float ssum = e;
        #pragma unroll
        for (int o = 8; o > 0; o >>= 1) ssum += __shfl_xor(ssum, o, 16);
        float aw = e / ssum;

        if (p < 12) {
            int l = p >> 2;
            float fS = (l == 0) ? 100.0f : ((l == 1) ? 50.0f : 25.0f);
            int   Wl = (l == 0) ? 100 : ((l == 1) ? 50 : 25);
            int   st = (l == 0) ? 0 : ((l == 1) ? 10000 : 12500);
            float x = (rx + oxy.x / fS) * fS - 0.5f;
            float y = (ry + oxy.y / fS) * fS - 0.5f;
            float x0f = floorf(x), y0f = floorf(y);
            float fx = x - x0f, fy = y - y0f;
            int x0 = (int)x0f, y0 = (int)y0f;
            int x1 = x0 + 1,  y1 = y0 + 1;
            int cx0 = imin(imax(x0, 0), Wl - 1), cx1 = imin(imax(x1, 0), Wl - 1);
            int cy0 = imin(imax(y0, 0), Wl - 1), cy1 = imin(imax(y1, 0), Wl - 1);
            float vx0 = (x0 >= 0 && x0 < Wl) ? 1.0f : 0.0f;
            float vx1 = (x1 >= 0 && x1 < Wl) ? 1.0f : 0.0f;
            float vy0 = (y0 >= 0 && y0 < Wl) ? 1.0f : 0.0f;
            float vy1 = (y1 >= 0 && y1 < Wl) ? 1.0f : 0.0f;
            int s = wid * 104 + h * 13 + p;
            metaIdx[s] = make_int4(st + cy0 * Wl + cx0, st + cy0 * Wl + cx1,
                                   st + cy1 * Wl + cx0, st + cy1 * Wl + cx1);
            metaW[s] = make_float4((1.0f - fx) * (1.0f - fy) * aw * vx0 * vy0,
                                   fx * (1.0f - fy) * aw * vx1 * vy0,
                                   (1.0f - fx) * fy * aw * vx0 * vy1,
                                   fx * fy * aw * vx1 * vy1);
        }
    }
    __syncthreads();

    int h  = lane >> 3;
    int c8 = lane & 7;
    const __hip_bfloat16* vbh = v + ((size_t)(b * HEADS + h)) * NVTOT * DHEAD + c8 * 4;
    float4 acc = {0.0f, 0.0f, 0.0f, 0.0f};
    #pragma unroll
    for (int p = 0; p < 12; p++) {
        int s = wid * 104 + h * 13 + p;
        int4   mi = metaIdx[s];
        float4 mw = metaW[s];
        ushort4 r0 = *(const ushort4*)(vbh + (size_t)mi.x * DHEAD);
        ushort4 r1 = *(const ushort4*)(vbh + (size_t)mi.y * DHEAD);
        ushort4 r2 = *(const ushort4*)(vbh + (size_t)mi.z * DHEAD);
        ushort4 r3 = *(const ushort4*)(vbh + (size_t)mi.w * DHEAD);
        acc.x = fmaf(mw.x, __uint_as_float((unsigned)r0.x << 16), acc.x);
        acc.y = fmaf(mw.x, __uint_as_float((unsigned)r0.y << 16), acc.y);
        acc.z = fmaf(mw.x, __uint_as_float((unsigned)r0.z << 16), acc.z);
        acc.w = fmaf(mw.x, __uint_as_float((unsigned)r0.w << 16), acc.w);
        acc.x = fmaf(mw.y, __uint_as_float((unsigned)r1.x << 16), acc.x);
        acc.y = fmaf(mw.y, __uint_as_float((unsigned)r1.y << 16), acc.y);
        acc.z = fmaf(mw.y, __uint_as_float((unsigned)r1.z << 16), acc.z);
        acc.w = fmaf(mw.y, __uint_as_float((unsigned)r1.w << 16), acc.w);
        acc.x = fmaf(mw.z, __uint_as_float((unsigned)r2.x << 16), acc.x);
        acc.y = fmaf(mw.z, __uint_as_float((unsigned)r2.y << 16), acc.y);
        acc.z = fmaf(mw.z, __uint_as_float((unsigned)r2.z << 16), acc.z);
        acc.w = fmaf(mw.z, __uint_as_float((unsigned)r2.w << 16), acc.w);
        acc.x = fmaf(mw.w, __uint_as_float((unsigned)r3.x << 16), acc.x);
        acc.y = fmaf(mw.w, __uint_as_float((unsigned)r3.y << 16), acc.y);
        acc.z = fmaf(mw.w, __uint_as_float((unsigned)r3.z << 16), acc.z);
        acc.w = fmaf(mw.w, __uint_as_float((unsigned)r3.w << 16), acc.w);
    }
    bf16x4 r;
    r.v[0] = __float2bfloat16(acc.x); r.v[1] = __float2bfloat16(acc.y);
    r.v[2] = __float2bfloat16(acc.z); r.v[3] = __float2bfloat16(acc.w);
    *(bf16x4*)(out + (size_t)t * CDIM + h * DHEAD + c8 * 4) = r;
}

// ---------------------------------------------------------------- launch
extern "C" void kernel_launch(void* const* d_in, const int* in_sizes, int n_in,
                              void* d_out, int out_size, void* d_ws, size_t ws_size,
                              hipStream_t stream)
{
    const float* query = (const float*)d_in[0];
    const float* value = (const float*)d_in[1];
    const float* qpos  = (const float*)d_in[2];
    const float* ref   = (const float*)d_in[3];
    const float* ln1g  = (const float*)d_in[6];
    const float* ln1b  = (const float*)d_in[7];
    const float* ln2g  = (const float*)d_in[8];
    const float* ln2b  = (const float*)d_in[9];
    const float* Wv    = (const float*)d_in[10];
    const float* bv    = (const float*)d_in[11];
    const float* Woff  = (const float*)d_in[12];
    const float* boff  = (const float*)d_in[13];
    const float* Wat   = (const float*)d_in[14];
    const float* bat   = (const float*)d_in[15];
    const float* Wout  = (const float*)d_in[16];
    const float* bout  = (const float*)d_in[17];
    const float* W1    = (const float*)d_in[18];
    const float* b1    = (const float*)d_in[19];
    const float* W2    = (const float*)d_in[20];
    const float* b2    = (const float*)d_in[21];
    float* out = (float*)d_out;
    char*  ws  = (char*)d_ws;

    const size_t MB = 1024 * 1024;
    __hip_bfloat16* Wvt   = (__hip_bfloat16*)(ws + 0);        // 256*256
    __hip_bfloat16* Wct   = (__hip_bfloat16*)(ws + 131072);   // 384*256 combined proj
    __hip_bfloat16* Woutt = (__hip_bfloat16*)(ws + 327680);   // 256*256
    __hip_bfloat16* W1t   = (__hip_bfloat16*)(ws + 458752);   // 1024*256
    __hip_bfloat16* W2t   = (__hip_bfloat16*)(ws + 983040);   // 256*1024
    float*          bcomb = (float*)(ws + 1507328);           // 288 floats
    __hip_bfloat16* qbf   = (__hip_bfloat16*)(ws + 2  * MB);  // 16.78 MB; reused as h
    __hip_bfloat16* aoutb = (__hip_bfloat16*)(ws + 19 * MB);  // 16.78 MB
    __hip_bfloat16* vbf   = (__hip_bfloat16*)(ws + 36 * MB);  // 13.44 MB (bf16 value input)
    __hip_bfloat16* vbuf  = (__hip_bfloat16*)(ws + 50 * MB);  // 13.44 MB scattered v (bf16)
    float*          cbuf  = (float*)(ws + 77 * MB);           // 37.75 MB fused proj (stride 288)
    __hip_bfloat16* gbf   = (__hip_bfloat16*)(ws + 50 * MB);  // 67.1 MB, aliases vbuf/cbuf (dead by FFN)
    __hip_bfloat16* hbf   = qbf;

    // 0. weights -> bf16 transposed (+ combined proj weight/bias), one launch
    wt_all_k<<<2946, 256, 0, stream>>>(Wv, Woff, Wat, Wout, W1, W2, boff, bat,
                                       Wvt, Wct, Woutt, W1t, W2t, bcomb);
    // 0b. value -> bf16
    cvt_k<<<(MROWS_V * CDIM / 4 + 255) / 256, 256, 0, stream>>>(value, vbf, MROWS_V * CDIM / 4);
    // 1. q = LN1(query) + query_pos  (bf16)
    ln_bf16_k<<<NTOK / 4, 256, 0, stream>>>(query, qpos, ln1g, ln1b, qbf);
    // 2. v = value @ W_value + b_value, scattered [b][h][pix][d] bf16
    mm_k<<<dim3((MROWS_V + 127) / 128, 2), 256, 0, stream>>>(
        vbf, Wvt, bv, nullptr, vbuf, MROWS_V, 256, 256, EP_VSCAT_BF16);
    // 3. fused proj: [offsets | attn logits] = q @ [W_off|W_attn] + [b_off|b_attn]
    mm_k<<<dim3(NTOK / 128, 3), 256, 0, stream>>>(
        qbf, Wct, bcomb, nullptr, cbuf, NTOK, NPROJ, 256, EP_PLAIN);
    // 4. sampling (inline softmax) -> aout bf16
    sample_k<<<NTOK / 4, 256, 0, stream>>>(vbuf, cbuf, ref, aoutb);
    // 5. x = query + aout @ W_out + b_out -> d_out fp32
    mm_k<<<dim3(NTOK / 128, 2), 256, 0, stream>>>(
        aoutb, Woutt, bout, query, out, NTOK, 256, 256, EP_RES);
    // 6. h = LN2(x)  bf16
    ln_bf16_k<<<NTOK / 4, 256, 0, stream>>>(out, nullptr, ln2g, ln2b, hbf);
    // 7. g = gelu(h @ W_ffn1 + b_ffn1)  bf16
    mm_k<<<dim3(NTOK / 128, 8), 256, 0, stream>>>(
        hbf, W1t, b1, nullptr, gbf, NTOK, FDIM, 256, EP_GELU_BF16);
    // 8. out = x + g @ W_ffn2 + b_ffn2  (in-place residual)
    mm_k<<<dim3(NTOK / 128, 2), 256, 0, stream>>>(
        gbf, W2t, b2, out, out, NTOK, 256, FDIM, EP_RES);
}

// Round 6
// 403.608 us; speedup vs baseline: 3.0072x; 1.1359x over previous
//
#include <hip/hip_runtime.h>
#include <hip/hip_bf16.h>

// Problem constants (fixed by setup_inputs)
#define BQ      2
#define QLEN    16384            // 128*128
#define CDIM    256
#define HEADS   8
#define LEV     3
#define PTS     4
#define DHEAD   32
#define NVTOT   13125            // 100*100 + 50*50 + 25*25
#define FDIM    1024
#define NTOK    (BQ*QLEN)        // 32768
#define MROWS_V (BQ*NVTOT)       // 26250
#define NPROJ   288              // 192 offsets + 96 attn logits, fused

typedef __attribute__((ext_vector_type(8))) short short8;     // 8 bf16 = 4 VGPRs
typedef __attribute__((ext_vector_type(4))) float floatx4;    // MFMA acc

typedef const __attribute__((address_space(1))) unsigned int gu32;
typedef __attribute__((address_space(3))) unsigned int lu32;

struct bf16x4 { __hip_bfloat16 v[4]; };

__device__ __forceinline__ int imin(int a, int b){ return a<b?a:b; }
__device__ __forceinline__ int imax(int a, int b){ return a>b?a:b; }

// saturation-safe fast gelu (tanh form); error ~3e-4 < bf16 rounding
__device__ __forceinline__ float gelu_f(float x)
{
    float u = 0.7978845608028654f * (x + 0.044715f * x * x * x);
    float e = __expf(2.0f * u);
    float th = 1.0f - 2.0f / (e + 1.0f);
    return 0.5f * x * (1.0f + th);
}

// ---------------------------------------------------------------- LayerNorm (+optional pos add), bf16 out
__global__ __launch_bounds__(256)
void ln_bf16_k(const float* __restrict__ x, const float* __restrict__ pos,
               const float* __restrict__ g, const float* __restrict__ b,
               __hip_bfloat16* __restrict__ out)
{
    int tok  = blockIdx.x * 4 + (threadIdx.x >> 6);
    int lane = threadIdx.x & 63;
    float4 v = ((const float4*)(x + (size_t)tok * CDIM))[lane];
    float s = v.x + v.y + v.z + v.w;
    #pragma unroll
    for (int o = 32; o > 0; o >>= 1) s += __shfl_down(s, o);
    s = __shfl(s, 0);
    float mean = s * (1.0f / 256.0f);
    float4 c; c.x = v.x - mean; c.y = v.y - mean; c.z = v.z - mean; c.w = v.w - mean;
    float q2 = c.x*c.x + c.y*c.y + c.z*c.z + c.w*c.w;
    #pragma unroll
    for (int o = 32; o > 0; o >>= 1) q2 += __shfl_down(q2, o);
    q2 = __shfl(q2, 0);
    float rstd = rsqrtf(q2 * (1.0f / 256.0f) + 1e-5f);
    float4 gg = ((const float4*)g)[lane];
    float4 bb = ((const float4*)b)[lane];
    float4 o4;
    o4.x = c.x * rstd * gg.x + bb.x;
    o4.y = c.y * rstd * gg.y + bb.y;
    o4.z = c.z * rstd * gg.z + bb.z;
    o4.w = c.w * rstd * gg.w + bb.w;
    if (pos) {
        float4 p = ((const float4*)(pos + (size_t)tok * CDIM))[lane];
        o4.x += p.x; o4.y += p.y; o4.z += p.z; o4.w += p.w;
    }
    bf16x4 r;
    r.v[0] = __float2bfloat16(o4.x); r.v[1] = __float2bfloat16(o4.y);
    r.v[2] = __float2bfloat16(o4.z); r.v[3] = __float2bfloat16(o4.w);
    ((bf16x4*)(out + (size_t)tok * CDIM))[lane] = r;
}

// ---------------------------------------------------------------- fp32 -> bf16 convert
__global__ __launch_bounds__(256)
void cvt_k(const float* __restrict__ in, __hip_bfloat16* __restrict__ out, int n4)
{
    int i = blockIdx.x * 256 + threadIdx.x;
    if (i >= n4) return;
    float4 v = ((const float4*)in)[i];
    bf16x4 r;
    r.v[0] = __float2bfloat16(v.x); r.v[1] = __float2bfloat16(v.y);
    r.v[2] = __float2bfloat16(v.z); r.v[3] = __float2bfloat16(v.w);
    ((bf16x4*)out)[i] = r;
}

// ---------------------------------------------------------------- fused weight transpose+convert (+combined proj weight & bias)
__global__ __launch_bounds__(256)
void wt_all_k(const float* __restrict__ Wv,  const float* __restrict__ Woff,
              const float* __restrict__ Wat, const float* __restrict__ Wout,
              const float* __restrict__ W1,  const float* __restrict__ W2,
              const float* __restrict__ boff, const float* __restrict__ bat,
              __hip_bfloat16* __restrict__ o_v,  __hip_bfloat16* __restrict__ o_c,
              __hip_bfloat16* __restrict__ o_out,
              __hip_bfloat16* __restrict__ o_1,  __hip_bfloat16* __restrict__ o_2,
              float* __restrict__ o_bc)
{
    int gid = blockIdx.x * 256 + threadIdx.x;
    if (gid < 65536) {                      // Wv  [256][256] -> [256][256]
        int idx = gid, n = idx >> 8, k = idx & 255;
        o_v[idx] = __float2bfloat16(Wv[(size_t)k * 256 + n]);
    } else if (gid < 163840) {              // combined proj -> [384][256]
        int idx = gid - 65536, n = idx >> 8, k = idx & 255;
        float v = 0.0f;
        if (n < 192)       v = Woff[(size_t)k * 192 + n];
        else if (n < 288)  v = Wat[(size_t)k * 96 + (n - 192)];
        o_c[idx] = __float2bfloat16(v);
    } else if (gid < 229376) {              // Wout [256][256]
        int idx = gid - 163840, n = idx >> 8, k = idx & 255;
        o_out[idx] = __float2bfloat16(Wout[(size_t)k * 256 + n]);
    } else if (gid < 491520) {              // W1 [256][1024] -> [1024][256]
        int idx = gid - 229376, n = idx >> 8, k = idx & 255;
        o_1[idx] = __float2bfloat16(W1[(size_t)k * 1024 + n]);
    } else if (gid < 753664) {              // W2 [1024][256] -> [256][1024]
        int idx = gid - 491520, n = idx >> 10, k = idx & 1023;
        o_2[idx] = __float2bfloat16(W2[(size_t)k * 256 + n]);
    } else if (gid < 753952) {              // combined bias [288]
        int idx = gid - 753664;
        o_bc[idx] = (idx < 192) ? boff[idx] : bat[idx - 192];
    }
}

// ---------------------------------------------------------------- bf16 MFMA GEMM (transposed-acc)
// Weights are the MFMA-A operand, tokens the MFMA-B operand -> D rows = channels,
// cols = tokens, so each lane's 4 acc regs are 4 CONSECUTIVE CHANNELS of one token
// -> vectorized float4/bf16x4 epilogue stores (16 wide stores vs 64 scalar).
// BK=64, XOR-swizzled LDS, grid=(tokTiles, chanTiles): token tile L2-reused across
// chanTiles on the same XCD.
enum { EP_PLAIN = 0, EP_VSCAT_BF16 = 1, EP_RES = 2, EP_GELU_BF16 = 3 };

__global__ __launch_bounds__(256)
void mm_k(const __hip_bfloat16* __restrict__ A, const __hip_bfloat16* __restrict__ Bt,
          const float* __restrict__ bias, const float* __restrict__ res,
          void* __restrict__ Cout, int M, int N, int K, int mode)
{
    __shared__ __hip_bfloat16 Ws[128 * 64];   // weight rows (channels)
    __shared__ __hip_bfloat16 Ts[128 * 64];   // token rows
    int t = threadIdx.x;
    int lane = t & 63;
    int wave = t >> 6;
    int wm = wave >> 1, wn = wave & 1;
    int lm = lane & 15, lk = lane >> 4;
    int m0 = blockIdx.x * 128;     // token base
    int n0 = blockIdx.y * 128;     // channel base

    floatx4 acc[4][4];             // [i: channel subtile][j: token subtile]
    #pragma unroll
    for (int i = 0; i < 4; i++)
        #pragma unroll
        for (int j = 0; j < 4; j++) acc[i][j] = (floatx4)0.0f;

    for (int kt = 0; kt < K; kt += 64) {
        #pragma unroll
        for (int i = 0; i < 4; i++) {
            int cc  = i * 256 + t;          // LDS chunk 0..1023 (16 B each)
            int row = cc >> 3;              // 0..127
            int c   = cc & 7;
            int kc  = c ^ (row & 7);        // XOR swizzle
            int ra  = m0 + row; if (ra >= M) ra = M - 1;   // token row clamp
            const __hip_bfloat16* gw = Bt + (size_t)(n0 + row) * K + kt + kc * 8;  // weights (padded N)
            const __hip_bfloat16* gt = A  + (size_t)ra * K + kt + kc * 8;          // tokens
            __builtin_amdgcn_global_load_lds((gu32*)gw, (lu32*)(Ws + cc * 8), 16, 0, 0);
            __builtin_amdgcn_global_load_lds((gu32*)gt, (lu32*)(Ts + cc * 8), 16, 0, 0);
        }
        __syncthreads();
        #pragma unroll
        for (int ks = 0; ks < 2; ks++) {
            short8 wf[4], tf[4];
            #pragma unroll
            for (int i = 0; i < 4; i++) {
                int rw = wn * 64 + i * 16 + lm;            // channel row
                int cw = (ks * 4 + lk) ^ (rw & 7);
                wf[i] = *(const short8*)(Ws + (rw * 8 + cw) * 8);
                int rt = wm * 64 + i * 16 + lm;            // token row
                int ct = (ks * 4 + lk) ^ (rt & 7);
                tf[i] = *(const short8*)(Ts + (rt * 8 + ct) * 8);
            }
            #pragma unroll
            for (int i = 0; i < 4; i++)
                #pragma unroll
                for (int j = 0; j < 4; j++)
                    acc[i][j] = __builtin_amdgcn_mfma_f32_16x16x32_bf16(wf[i], tf[j], acc[i][j], 0, 0, 0);
        }
        __syncthreads();
    }

    // epilogue: D col = lane&15 -> token, D row = lk*4+reg -> channel
    // lane's 4 regs = 4 consecutive channels of one token -> wide stores.
    #pragma unroll
    for (int i = 0; i < 4; i++) {
        int chan = n0 + wn * 64 + i * 16 + lk * 4;
        float4 b4 = make_float4(0.f, 0.f, 0.f, 0.f);
        if (chan < N) b4 = *(const float4*)(bias + chan);
        #pragma unroll
        for (int j = 0; j < 4; j++) {
            int tok = m0 + wm * 64 + j * 16 + lm;
            if (tok >= M || chan >= N) continue;
            float4 v;
            v.x = acc[i][j][0] + b4.x;
            v.y = acc[i][j][1] + b4.y;
            v.z = acc[i][j][2] + b4.z;
            v.w = acc[i][j][3] + b4.w;
            if (mode == EP_PLAIN) {
                *(float4*)((float*)Cout + (size_t)tok * N + chan) = v;
            } else if (mode == EP_VSCAT_BF16) {
                int bb  = tok / NVTOT;
                int pix = tok - bb * NVTOT;
                int hh  = chan >> 5, dc = chan & 31;
                bf16x4 r;
                r.v[0] = __float2bfloat16(v.x); r.v[1] = __float2bfloat16(v.y);
                r.v[2] = __float2bfloat16(v.z); r.v[3] = __float2bfloat16(v.w);
                *(bf16x4*)((__hip_bfloat16*)Cout
                    + (((size_t)(bb * HEADS + hh)) * NVTOT + pix) * DHEAD + dc) = r;
            } else if (mode == EP_RES) {
                float4 rr = *(const float4*)(res + (size_t)tok * N + chan);
                v.x += rr.x; v.y += rr.y; v.z += rr.z; v.w += rr.w;
                *(float4*)((float*)Cout + (size_t)tok * N + chan) = v;
            } else { // EP_GELU_BF16
                bf16x4 r;
                r.v[0] = __float2bfloat16(gelu_f(v.x));
                r.v[1] = __float2bfloat16(gelu_f(v.y));
                r.v[2] = __float2bfloat16(gelu_f(v.z));
                r.v[3] = __float2bfloat16(gelu_f(v.w));
                *(bf16x4*)((__hip_bfloat16*)Cout + (size_t)tok * N + chan) = r;
            }
        }
    }
}

// ---------------------------------------------------------------- deformable sampling (inline softmax)
__global__ __launch_bounds__(256)
void sample_k(const __hip_bfloat16* __restrict__ v, const float* __restrict__ cbuf,
              const float* __restrict__ ref, __hip_bfloat16* __restrict__ out)
{
    __shared__ int4   metaIdx[4 * 104];   // stride 13 slots -> conflict-free
    __shared__ float4 metaW[4 * 104];

    int wid  = threadIdx.x >> 6;
    int lane = threadIdx.x & 63;
    int t    = blockIdx.x * 4 + wid;
    int b    = t >> 14;
    float rx = ref[(size_t)t * 2 + 0];
    float ry = ref[(size_t)t * 2 + 1];
    const float* crow = cbuf + (size_t)t * NPROJ;

    #pragma unroll
    for (int rnd = 0; rnd < 2; rnd++) {
        int slot = rnd * 64 + lane;
        int h = slot >> 4, p = slot & 15;
        int pc = imin(p, 11);
        float2 oxy  = *(const float2*)(crow + h * 24 + pc * 2);
        float logit = crow[192 + h * 12 + pc];
        float mx = logit;
        #pragma unroll
        for (int o = 8; o > 0; o >>= 1) mx = fmaxf(mx, __shfl_xor(mx, o, 16));
        float e = (p < 12) ? __expf(logit - mx) : 0.0f;
        float ssum = e;
        #pragma unroll
        for (int o = 8; o > 0; o >>= 1) ssum += __shfl_xor(ssum, o, 16);
        float aw = e / ssum;

        if (p < 12) {
            int l = p >> 2;
            float fS = (l == 0) ? 100.0f : ((l == 1) ? 50.0f : 25.0f);
            int   Wl = (l == 0) ? 100 : ((l == 1) ? 50 : 25);
            int   st = (l == 0) ? 0 : ((l == 1) ? 10000 : 12500);
            float x = (rx + oxy.x / fS) * fS - 0.5f;
            float y = (ry + oxy.y / fS) * fS - 0.5f;
            float x0f = floorf(x), y0f = floorf(y);
            float fx = x - x0f, fy = y - y0f;
            int x0 = (int)x0f, y0 = (int)y0f;
            int x1 = x0 + 1,  y1 = y0 + 1;
            int cx0 = imin(imax(x0, 0), Wl - 1), cx1 = imin(imax(x1, 0), Wl - 1);
            int cy0 = imin(imax(y0, 0), Wl - 1), cy1 = imin(imax(y1, 0), Wl - 1);
            float vx0 = (x0 >= 0 && x0 < Wl) ? 1.0f : 0.0f;
            float vx1 = (x1 >= 0 && x1 < Wl) ? 1.0f : 0.0f;
            float vy0 = (y0 >= 0 && y0 < Wl) ? 1.0f : 0.0f;
            float vy1 = (y1 >= 0 && y1 < Wl) ? 1.0f : 0.0f;
            int s = wid * 104 + h * 13 + p;
            metaIdx[s] = make_int4(st + cy0 * Wl + cx0, st + cy0 * Wl + cx1,
                                   st + cy1 * Wl + cx0, st + cy1 * Wl + cx1);
            metaW[s] = make_float4((1.0f - fx) * (1.0f - fy) * aw * vx0 * vy0,
                                   fx * (1.0f - fy) * aw * vx1 * vy0,
                                   (1.0f - fx) * fy * aw * vx0 * vy1,
                                   fx * fy * aw * vx1 * vy1);
        }
    }
    __syncthreads();

    int h  = lane >> 3;
    int c8 = lane & 7;
    const __hip_bfloat16* vbh = v + ((size_t)(b * HEADS + h)) * NVTOT * DHEAD + c8 * 4;
    float4 acc = {0.0f, 0.0f, 0.0f, 0.0f};
    #pragma unroll
    for (int p = 0; p < 12; p++) {
        int s = wid * 104 + h * 13 + p;
        int4   mi = metaIdx[s];
        float4 mw = metaW[s];
        ushort4 r0 = *(const ushort4*)(vbh + (size_t)mi.x * DHEAD);
        ushort4 r1 = *(const ushort4*)(vbh + (size_t)mi.y * DHEAD);
        ushort4 r2 = *(const ushort4*)(vbh + (size_t)mi.z * DHEAD);
        ushort4 r3 = *(const ushort4*)(vbh + (size_t)mi.w * DHEAD);
        acc.x = fmaf(mw.x, __uint_as_float((unsigned)r0.x << 16), acc.x);
        acc.y = fmaf(mw.x, __uint_as_float((unsigned)r0.y << 16), acc.y);
        acc.z = fmaf(mw.x, __uint_as_float((unsigned)r0.z << 16), acc.z);
        acc.w = fmaf(mw.x, __uint_as_float((unsigned)r0.w << 16), acc.w);
        acc.x = fmaf(mw.y, __uint_as_float((unsigned)r1.x << 16), acc.x);
        acc.y = fmaf(mw.y, __uint_as_float((unsigned)r1.y << 16), acc.y);
        acc.z = fmaf(mw.y, __uint_as_float((unsigned)r1.z << 16), acc.z);
        acc.w = fmaf(mw.y, __uint_as_float((unsigned)r1.w << 16), acc.w);
        acc.x = fmaf(mw.z, __uint_as_float((unsigned)r2.x << 16), acc.x);
        acc.y = fmaf(mw.z, __uint_as_float((unsigned)r2.y << 16), acc.y);
        acc.z = fmaf(mw.z, __uint_as_float((unsigned)r2.z << 16), acc.z);
        acc.w = fmaf(mw.z, __uint_as_float((unsigned)r2.w << 16), acc.w);
        acc.x = fmaf(mw.w, __uint_as_float((unsigned)r3.x << 16), acc.x);
        acc.y = fmaf(mw.w, __uint_as_float((unsigned)r3.y << 16), acc.y);
        acc.z = fmaf(mw.w, __uint_as_float((unsigned)r3.z << 16), acc.z);
        acc.w = fmaf(mw.w, __uint_as_float((unsigned)r3.w << 16), acc.w);
    }
    bf16x4 r;
    r.v[0] = __float2bfloat16(acc.x); r.v[1] = __float2bfloat16(acc.y);
    r.v[2] = __float2bfloat16(acc.z); r.v[3] = __float2bfloat16(acc.w);
    *(bf16x4*)(out + (size_t)t * CDIM + h * DHEAD + c8 * 4) = r;
}

// ---------------------------------------------------------------- launch
extern "C" void kernel_launch(void* const* d_in, const int* in_sizes, int n_in,
                              void* d_out, int out_size, void* d_ws, size_t ws_size,
                              hipStream_t stream)
{
    const float* query = (const float*)d_in[0];
    const float* value = (const float*)d_in[1];
    const float* qpos  = (const float*)d_in[2];
    const float* ref   = (const float*)d_in[3];
    const float* ln1g  = (const float*)d_in[6];
    const float* ln1b  = (const float*)d_in[7];
    const float* ln2g  = (const float*)d_in[8];
    const float* ln2b  = (const float*)d_in[9];
    const float* Wv    = (const float*)d_in[10];
    const float* bv    = (const float*)d_in[11];
    const float* Woff  = (const float*)d_in[12];
    const float* boff  = (const float*)d_in[13];
    const float* Wat   = (const float*)d_in[14];
    const float* bat   = (const float*)d_in[15];
    const float* Wout  = (const float*)d_in[16];
    const float* bout  = (const float*)d_in[17];
    const float* W1    = (const float*)d_in[18];
    const float* b1    = (const float*)d_in[19];
    const float* W2    = (const float*)d_in[20];
    const float* b2    = (const float*)d_in[21];
    float* out = (float*)d_out;
    char*  ws  = (char*)d_ws;

    const size_t MB = 1024 * 1024;
    __hip_bfloat16* Wvt   = (__hip_bfloat16*)(ws + 0);        // 256*256
    __hip_bfloat16* Wct   = (__hip_bfloat16*)(ws + 131072);   // 384*256 combined proj
    __hip_bfloat16* Woutt = (__hip_bfloat16*)(ws + 327680);   // 256*256
    __hip_bfloat16* W1t   = (__hip_bfloat16*)(ws + 458752);   // 1024*256
    __hip_bfloat16* W2t   = (__hip_bfloat16*)(ws + 983040);   // 256*1024
    float*          bcomb = (float*)(ws + 1507328);           // 288 floats
    __hip_bfloat16* qbf   = (__hip_bfloat16*)(ws + 2  * MB);  // 16.78 MB; reused as h
    __hip_bfloat16* aoutb = (__hip_bfloat16*)(ws + 19 * MB);  // 16.78 MB
    __hip_bfloat16* vbf   = (__hip_bfloat16*)(ws + 36 * MB);  // 13.44 MB (bf16 value input)
    __hip_bfloat16* vbuf  = (__hip_bfloat16*)(ws + 50 * MB);  // 13.44 MB scattered v (bf16)
    float*          cbuf  = (float*)(ws + 77 * MB);           // 37.75 MB fused proj (stride 288)
    __hip_bfloat16* gbf   = (__hip_bfloat16*)(ws + 50 * MB);  // 67.1 MB, aliases vbuf/cbuf (dead by FFN)
    __hip_bfloat16* hbf   = qbf;

    // 0. weights -> bf16 transposed (+ combined proj weight/bias), one launch
    wt_all_k<<<2946, 256, 0, stream>>>(Wv, Woff, Wat, Wout, W1, W2, boff, bat,
                                       Wvt, Wct, Woutt, W1t, W2t, bcomb);
    // 0b. value -> bf16
    cvt_k<<<(MROWS_V * CDIM / 4 + 255) / 256, 256, 0, stream>>>(value, vbf, MROWS_V * CDIM / 4);
    // 1. q = LN1(query) + query_pos  (bf16)
    ln_bf16_k<<<NTOK / 4, 256, 0, stream>>>(query, qpos, ln1g, ln1b, qbf);
    // 2. v = value @ W_value + b_value, scattered [b][h][pix][d] bf16
    mm_k<<<dim3((MROWS_V + 127) / 128, 2), 256, 0, stream>>>(
        vbf, Wvt, bv, nullptr, vbuf, MROWS_V, 256, 256, EP_VSCAT_BF16);
    // 3. fused proj: [offsets | attn logits] = q @ [W_off|W_attn] + [b_off|b_attn]
    mm_k<<<dim3(NTOK / 128, 3), 256, 0, stream>>>(
        qbf, Wct, bcomb, nullptr, cbuf, NTOK, NPROJ, 256, EP_PLAIN);
    // 4. sampling (inline softmax) -> aout bf16
    sample_k<<<NTOK / 4, 256, 0, stream>>>(vbuf, cbuf, ref, aoutb);
    // 5. x = query + aout @ W_out + b_out -> d_out fp32
    mm_k<<<dim3(NTOK / 128, 2), 256, 0, stream>>>(
        aoutb, Woutt, bout, query, out, NTOK, 256, 256, EP_RES);
    // 6. h = LN2(x)  bf16
    ln_bf16_k<<<NTOK / 4, 256, 0, stream>>>(out, nullptr, ln2g, ln2b, hbf);
    // 7. g = gelu(h @ W_ffn1 + b_ffn1)  bf16
    mm_k<<<dim3(NTOK / 128, 8), 256, 0, stream>>>(
        hbf, W1t, b1, nullptr, gbf, NTOK, FDIM, 256, EP_GELU_BF16);
    // 8. out = x + g @ W_ffn2 + b_ffn2  (in-place residual)
    mm_k<<<dim3(NTOK / 128, 2), 256, 0, stream>>>(
        gbf, W2t, b2, out, out, NTOK, 256, FDIM, EP_RES);
}